// Round 15
// baseline (435.447 us; speedup 1.0000x reference)
//
#include <hip/hip_runtime.h>
#include <math.h>

#define NN 50000
#define NE 800000
#define KS 500
#define NSL 8
#define SLICE 63

typedef unsigned short ushort_t;
typedef unsigned int uint_t;
typedef short bf16x8 __attribute__((ext_vector_type(8)));
typedef float f32x4 __attribute__((ext_vector_type(4)));

__device__ __forceinline__ float bf2f(ushort_t u) {
    return __uint_as_float(((uint_t)u) << 16);
}
__device__ __forceinline__ ushort_t f2bf(float f) {
    uint_t u = __float_as_uint(f);
    u += 0x7fffu + ((u >> 16) & 1u);   // round-to-nearest-even
    return (ushort_t)(u >> 16);
}
// fast silu: x * rcp(1+exp(-x)) using v_rcp_f32 (~1e-5 rel err) — NOT for the score path
__device__ __forceinline__ float fsilu(float x) {
    return x * __builtin_amdgcn_rcpf(1.f + __expf(-x));
}

// ============================ weight prep ============================
__global__ __launch_bounds__(128) void prep_wt(
    const float* __restrict__ Wa, const float* __restrict__ Wb, const float* __restrict__ W3,
    ushort_t* __restrict__ Wta, ushort_t* __restrict__ Wtb, ushort_t* __restrict__ Wt3a)
{
    int j = blockIdx.x;      // output row = original col
    int k = threadIdx.x;
    int y = blockIdx.y;
    const float* src = (y == 0) ? Wa : (y == 1) ? Wb : W3;
    ushort_t* dst = (y == 0) ? Wta : (y == 1) ? Wtb : Wt3a;
    dst[j * 128 + k] = f2bf(src[k * 128 + j]);
}

// W23t[j][c] = bf16(sum_k W2[c][k]*W3[128+k][j]); block 128 does b23[j]
__global__ __launch_bounds__(128) void w23t_kernel(
    const float* __restrict__ W2, const float* __restrict__ W3, const float* __restrict__ b2,
    ushort_t* __restrict__ W23t, float* __restrict__ b23)
{
    int c = blockIdx.x;
    int j = threadIdx.x;
    if (c < 128) {
        float acc = 0.f;
        for (int k = 0; k < 128; ++k) acc = fmaf(W2[c * 128 + k], W3[(128 + k) * 128 + j], acc);
        W23t[j * 128 + c] = f2bf(acc);
    } else {
        float acc = 0.f;
        for (int k = 0; k < 128; ++k) acc = fmaf(b2[k], W3[(128 + k) * 128 + j], acc);
        b23[j] = acc;
    }
}

// ============================ MFMA GEMM kernels ============================
// a16 = bf16(h@W_a), b16 = bf16(h@W_b). A-tile + per-kk weight K-slices staged in LDS.
__global__ __launch_bounds__(512) void mfma_dual(
    const float* __restrict__ h, const ushort_t* __restrict__ Wta, const ushort_t* __restrict__ Wtb,
    ushort_t* __restrict__ C1, ushort_t* __restrict__ C2, int M)
{
    __shared__ ushort_t As[64][136];
    __shared__ ushort_t Wa_s[128][40];
    __shared__ ushort_t Wb_s[128][40];
    const int t = threadIdx.x;
    const int bm = blockIdx.x * 64;
    for (int idx = t * 4; idx < 64 * 128; idx += 2048) {
        int r = idx >> 7, c = idx & 127;
        int gr = bm + r;
        float4 v = make_float4(0.f, 0.f, 0.f, 0.f);
        if (gr < M) v = *(const float4*)(h + (size_t)gr * 128 + c);
        As[r][c + 0] = f2bf(v.x); As[r][c + 1] = f2bf(v.y);
        As[r][c + 2] = f2bf(v.z); As[r][c + 3] = f2bf(v.w);
    }
    const int w = t >> 6;
    const int lane = t & 63;
    const int rowgrp = w >> 1;
    const int mat = w & 1;
    const int i = lane & 15, g = lane >> 4;
    const int row = rowgrp * 16 + i;
    const ushort_t* wsrc = (t < 256) ? Wta : Wtb;
    ushort_t* wdst0 = (t < 256) ? &Wa_s[0][0] : &Wb_s[0][0];
    const int tt = t & 255;
    const int wr = tt >> 1, wc = (tt & 1) * 16;

    f32x4 acc[8];
#pragma unroll
    for (int n = 0; n < 8; ++n) acc[n] = (f32x4)0.f;

#pragma unroll
    for (int kk = 0; kk < 4; ++kk) {
        __syncthreads();
        {
            uint4 v0 = *(const uint4*)(wsrc + (size_t)wr * 128 + kk * 32 + wc);
            uint4 v1 = *(const uint4*)(wsrc + (size_t)wr * 128 + kk * 32 + wc + 8);
            *(uint4*)(wdst0 + wr * 40 + wc) = v0;
            *(uint4*)(wdst0 + wr * 40 + wc + 8) = v1;
        }
        __syncthreads();
        const ushort_t* Ws = mat ? &Wb_s[0][0] : &Wa_s[0][0];
        bf16x8 af = *(const bf16x8*)(&As[row][kk * 32 + g * 8]);
#pragma unroll
        for (int n = 0; n < 8; ++n) {
            bf16x8 bf = *(const bf16x8*)(Ws + (n * 16 + i) * 40 + g * 8);
            acc[n] = __builtin_amdgcn_mfma_f32_16x16x32_bf16(af, bf, acc[n], 0, 0, 0);
        }
    }
    ushort_t* C = mat ? C2 : C1;
    const int R = bm + rowgrp * 16;
#pragma unroll
    for (int n = 0; n < 8; ++n) {
        int col = n * 16 + i;
#pragma unroll
        for (int v = 0; v < 4; ++v) {
            int orow = R + 4 * g + v;
            if (orow < M) C[(size_t)orow * 128 + col] = f2bf(acc[n][v]);
        }
    }
}

// out[:,0:128] = h + h@W3a + u16@W23 + cw*b23 + b3 ; out[:,128:256] = h_global
__global__ __launch_bounds__(512) void mfma_local_fused(
    const float* __restrict__ h, const ushort_t* __restrict__ u16,
    const ushort_t* __restrict__ Wt3a, const ushort_t* __restrict__ W23t,
    const float* __restrict__ b23, const float* __restrict__ b3,
    const float* __restrict__ cw, const float* __restrict__ h_global,
    float* __restrict__ out, int M)
{
    __shared__ ushort_t Hs[64][136];
    __shared__ ushort_t Us[64][136];
    __shared__ ushort_t W3s[128][40];
    __shared__ ushort_t W2s[128][40];
    const int t = threadIdx.x;
    const int bm = blockIdx.x * 64;
    for (int idx = t * 4; idx < 64 * 128; idx += 2048) {
        int r = idx >> 7, c = idx & 127;
        int gr = bm + r;
        float4 v = make_float4(0.f, 0.f, 0.f, 0.f);
        uint2 uv = make_uint2(0, 0);
        if (gr < M) {
            v = *(const float4*)(h + (size_t)gr * 128 + c);
            uv = *(const uint2*)(u16 + (size_t)gr * 128 + c);
            float4 hgv = *(const float4*)(h_global + (size_t)gr * 128 + c);
            *(float4*)(out + (size_t)gr * 256 + 128 + c) = hgv;   // global-half copy
        }
        Hs[r][c + 0] = f2bf(v.x); Hs[r][c + 1] = f2bf(v.y);
        Hs[r][c + 2] = f2bf(v.z); Hs[r][c + 3] = f2bf(v.w);
        Us[r][c + 0] = (ushort_t)(uv.x & 0xffff); Us[r][c + 1] = (ushort_t)(uv.x >> 16);
        Us[r][c + 2] = (ushort_t)(uv.y & 0xffff); Us[r][c + 3] = (ushort_t)(uv.y >> 16);
    }
    const int w = t >> 6;
    const int lane = t & 63;
    const int rowgrp = w >> 1;
    const int nb = (w & 1) * 4;
    const int i = lane & 15, g = lane >> 4;
    const int row = rowgrp * 16 + i;
    const ushort_t* wsrc = (t < 256) ? Wt3a : W23t;
    ushort_t* wdst0 = (t < 256) ? &W3s[0][0] : &W2s[0][0];
    const int tt = t & 255;
    const int wr = tt >> 1, wc = (tt & 1) * 16;

    f32x4 acc[4];
#pragma unroll
    for (int n = 0; n < 4; ++n) acc[n] = (f32x4)0.f;

#pragma unroll
    for (int kk = 0; kk < 4; ++kk) {
        __syncthreads();
        {
            uint4 v0 = *(const uint4*)(wsrc + (size_t)wr * 128 + kk * 32 + wc);
            uint4 v1 = *(const uint4*)(wsrc + (size_t)wr * 128 + kk * 32 + wc + 8);
            *(uint4*)(wdst0 + wr * 40 + wc) = v0;
            *(uint4*)(wdst0 + wr * 40 + wc + 8) = v1;
        }
        __syncthreads();
        bf16x8 aH = *(const bf16x8*)(&Hs[row][kk * 32 + g * 8]);
        bf16x8 aU = *(const bf16x8*)(&Us[row][kk * 32 + g * 8]);
#pragma unroll
        for (int n = 0; n < 4; ++n) {
            bf16x8 b3f = *(const bf16x8*)(&W3s[(nb + n) * 16 + i][g * 8]);
            bf16x8 b2f = *(const bf16x8*)(&W2s[(nb + n) * 16 + i][g * 8]);
            acc[n] = __builtin_amdgcn_mfma_f32_16x16x32_bf16(aH, b3f, acc[n], 0, 0, 0);
            acc[n] = __builtin_amdgcn_mfma_f32_16x16x32_bf16(aU, b2f, acc[n], 0, 0, 0);
        }
    }
    const int R = bm + rowgrp * 16;
    float cwv[4];
#pragma unroll
    for (int v = 0; v < 4; ++v) {
        int orow = R + 4 * g + v;
        cwv[v] = (orow < M) ? cw[orow] : 0.f;
    }
#pragma unroll
    for (int n = 0; n < 4; ++n) {
        int col = (nb + n) * 16 + i;
        float b3v = b3[col];
        float b23v = b23[col];
#pragma unroll
        for (int v = 0; v < 4; ++v) {
            int orow = R + 4 * g + v;
            if (orow < M) {
                float res = bf2f(Hs[rowgrp * 16 + 4 * g + v][col]);
                out[(size_t)orow * 256 + col] = acc[n][v] + b3v + cwv[v] * b23v + res;
            }
        }
    }
}

// fused fp32 score: mout = sigmoid(silu(hs@Wm1 + bm1)@Wm2 + bm2), hs = h_global[:, 0:64]
__global__ __launch_bounds__(256) void score_fused(
    const float* __restrict__ h_global, const float* __restrict__ Wm1,
    const float* __restrict__ bm1, const float* __restrict__ Wm2,
    const float* __restrict__ bm2, float* __restrict__ mout)
{
    __shared__ float Hs[64][64];
    const int t = threadIdx.x;
    const int bm = blockIdx.x * 64;
    for (int idx = t * 4; idx < 64 * 64; idx += 1024) {
        int r = idx >> 6, c = idx & 63;
        int gr = bm + r;
        float4 v = make_float4(0.f, 0.f, 0.f, 0.f);
        if (gr < NN) v = *(const float4*)(h_global + (size_t)gr * 128 + c);
        *(float4*)(&Hs[r][c]) = v;
    }
    __syncthreads();
    const int col = (t & 31) * 4;
    const int r0 = (t >> 5) * 8;
    float4 bmv = *(const float4*)(bm1 + col);
    float4 acc[8];
#pragma unroll
    for (int r = 0; r < 8; ++r) acc[r] = bmv;
    for (int k = 0; k < 64; ++k) {
        float4 w = *(const float4*)(Wm1 + k * 128 + col);
#pragma unroll
        for (int r = 0; r < 8; ++r) {
            float av = Hs[r0 + r][k];
            acc[r].x = fmaf(av, w.x, acc[r].x);
            acc[r].y = fmaf(av, w.y, acc[r].y);
            acc[r].z = fmaf(av, w.z, acc[r].z);
            acc[r].w = fmaf(av, w.w, acc[r].w);
        }
    }
    float4 w2v = *(const float4*)(Wm2 + col);
    float pr[8];
#pragma unroll
    for (int r = 0; r < 8; ++r) {
        float s = 0.f;
        s = fmaf(acc[r].x / (1.f + expf(-acc[r].x)), w2v.x, s);
        s = fmaf(acc[r].y / (1.f + expf(-acc[r].y)), w2v.y, s);
        s = fmaf(acc[r].z / (1.f + expf(-acc[r].z)), w2v.z, s);
        s = fmaf(acc[r].w / (1.f + expf(-acc[r].w)), w2v.w, s);
        pr[r] = s;
    }
#pragma unroll
    for (int off = 1; off < 32; off <<= 1) {
#pragma unroll
        for (int r = 0; r < 8; ++r) pr[r] += __shfl_xor(pr[r], off, 64);
    }
    if ((t & 31) == 0) {
        float bm2v = bm2[0];
#pragma unroll
        for (int r = 0; r < 8; ++r) {
            int gr = bm + r0 + r;
            if (gr < NN) mout[gr] = 1.f / (1.f + expf(-(pr[r] + bm2v)));
        }
    }
}

// f32 VALU gemm for the small master pass (KS=500)
__global__ __launch_bounds__(256) void gemm_dual(
    const float* __restrict__ A, const float* __restrict__ W1, const float* __restrict__ W2,
    float* __restrict__ C1, float* __restrict__ C2, int M, int ldc)
{
    __shared__ float As[64][128];
    const int t = threadIdx.x;
    const int bm = blockIdx.x * 64;
    for (int idx = t * 4; idx < 64 * 128; idx += 1024) {
        int r = idx >> 7, c = idx & 127;
        int gr = bm + r;
        float4 v = make_float4(0.f, 0.f, 0.f, 0.f);
        if (gr < M) v = *(const float4*)(A + (size_t)gr * 128 + c);
        *(float4*)(&As[r][c]) = v;
    }
    __syncthreads();
    const int col = (t & 31) * 4;
    const int r0 = (t >> 5) * 8;
    float4 acc1[8], acc2[8];
#pragma unroll
    for (int r = 0; r < 8; ++r) { acc1[r] = make_float4(0,0,0,0); acc2[r] = make_float4(0,0,0,0); }
    for (int k = 0; k < 128; ++k) {
        float4 w1 = *(const float4*)(W1 + k * 128 + col);
        float4 w2 = *(const float4*)(W2 + k * 128 + col);
#pragma unroll
        for (int r = 0; r < 8; ++r) {
            float av = As[r0 + r][k];
            acc1[r].x = fmaf(av, w1.x, acc1[r].x);
            acc1[r].y = fmaf(av, w1.y, acc1[r].y);
            acc1[r].z = fmaf(av, w1.z, acc1[r].z);
            acc1[r].w = fmaf(av, w1.w, acc1[r].w);
            acc2[r].x = fmaf(av, w2.x, acc2[r].x);
            acc2[r].y = fmaf(av, w2.y, acc2[r].y);
            acc2[r].z = fmaf(av, w2.z, acc2[r].z);
            acc2[r].w = fmaf(av, w2.w, acc2[r].w);
        }
    }
#pragma unroll
    for (int r = 0; r < 8; ++r) {
        int gr = bm + r0 + r;
        if (gr < M) {
            *(float4*)(C1 + (size_t)gr * ldc + col) = acc1[r];
            *(float4*)(C2 + (size_t)gr * ldc + col) = acc2[r];
        }
    }
}

// ============================ top-K (4x8-bit radix, fused scan via last-block) ============================
// state layout: [0..255] bins, [256] prefix, [257] remaining, [258] gt, [259] tie,
//               [260..263] done[level], [264] scan_part done, [265] select done
__global__ __launch_bounds__(256) void hist_fused(const float* __restrict__ m, int* state, int level)
{
    __shared__ int lh[256];
    __shared__ int amLast;
    lh[threadIdx.x] = 0;
    if (threadIdx.x == 0) amLast = 0;
    __syncthreads();
    int i = blockIdx.x * 256 + threadIdx.x;
    if (i < NN) {
        unsigned v = __float_as_uint(m[i]);
        int shift = 32 - 8 * level;
        bool ok = (level == 0) || ((v >> shift) == (unsigned)state[256]);
        if (ok) atomicAdd(&lh[(v >> (shift - 8)) & 255u], 1);
    }
    __syncthreads();
    if (lh[threadIdx.x]) atomicAdd(&state[threadIdx.x], lh[threadIdx.x]);
    __threadfence();
    __syncthreads();
    if (threadIdx.x == 0) {
        if (atomicAdd(&state[260 + level], 1) == (int)gridDim.x - 1) amLast = 1;
    }
    __syncthreads();
    if (amLast && threadIdx.x == 0) {
        __threadfence();
        int remaining = (level == 0) ? KS : state[257];
        int cum = 0, bin = 0;
        for (int b = 255; b >= 0; --b) {
            int c = state[b];
            if (cum + c >= remaining) { bin = b; remaining -= cum; break; }
            cum += c;
        }
        state[256] = (level == 0) ? bin : (int)(((unsigned)state[256] << 8) | (unsigned)bin);
        state[257] = remaining;
        for (int b = 0; b < 256; ++b) state[b] = 0;
    }
}

// select + tie-resolve fused via last-block
__global__ __launch_bounds__(256) void select_fused(const float* __restrict__ m, int* state,
                                                    int* sel, int* tie_buf)
{
    __shared__ int amLast;
    if (threadIdx.x == 0) amLast = 0;
    __syncthreads();
    int i = blockIdx.x * 256 + threadIdx.x;
    if (i < NN) {
        unsigned v = __float_as_uint(m[i]);
        unsigned T = (unsigned)state[256];
        if (v > T) {
            sel[atomicAdd(&state[258], 1)] = i;
        } else if (v == T) {
            int p = atomicAdd(&state[259], 1);
            if (p < 4096) tie_buf[p] = i;
        }
    }
    __threadfence();
    __syncthreads();
    if (threadIdx.x == 0) {
        if (atomicAdd(&state[265], 1) == (int)gridDim.x - 1) amLast = 1;
    }
    __syncthreads();
    if (amLast) {
        __threadfence();
        int need = state[257];
        int cgt = state[258];
        int tcount = state[259];
        if (tcount > 4096) tcount = 4096;
        for (int t2 = threadIdx.x; t2 < tcount; t2 += 256) {
            int id = tie_buf[t2];
            int rk = 0;
            for (int u = 0; u < tcount; ++u) rk += (tie_buf[u] < id);
            if (rk < need) sel[cgt + rk] = id;
        }
    }
}

__global__ __launch_bounds__(128) void build_master(
    const int* __restrict__ sel, const float* __restrict__ h_global,
    const float* __restrict__ pos, int* __restrict__ is_master, int* __restrict__ inv,
    float* __restrict__ h_m, float* __restrict__ pos_m)
{
    int r = blockIdx.x;
    int t = threadIdx.x;
    int node = sel[r];
    if (t == 0) {
        is_master[node] = 1;
        inv[node] = r;
        pos_m[r * 3 + 0] = pos[(size_t)node * 3 + 0];
        pos_m[r * 3 + 1] = pos[(size_t)node * 3 + 1];
        pos_m[r * 3 + 2] = pos[(size_t)node * 3 + 2];
    }
    h_m[(size_t)r * 128 + t] = h_global[(size_t)node * 128 + t];
}

// ============================ CSR build (group edges by dst) ============================
__global__ __launch_bounds__(256) void deg_hist(const int* __restrict__ ei, int* __restrict__ deg,
                                                int* __restrict__ rank)
{
    int e = blockIdx.x * 256 + threadIdx.x;
    if (e < NE) rank[e] = atomicAdd(&deg[ei[NE + e]], 1);
}

// per-block partial sums + last-block serial exclusive scan of partials
__global__ __launch_bounds__(256) void scan_part_fused(const int* __restrict__ deg,
                                                       int* __restrict__ part, int* state)
{
    __shared__ int red[256];
    __shared__ int amLast;
    if (threadIdx.x == 0) amLast = 0;
    int i = blockIdx.x * 256 + threadIdx.x;
    red[threadIdx.x] = (i < NN) ? deg[i] : 0;
    __syncthreads();
    for (int off = 128; off > 0; off >>= 1) {
        if (threadIdx.x < off) red[threadIdx.x] += red[threadIdx.x + off];
        __syncthreads();
    }
    if (threadIdx.x == 0) part[blockIdx.x] = red[0];
    __threadfence();
    __syncthreads();
    if (threadIdx.x == 0) {
        if (atomicAdd(&state[264], 1) == (int)gridDim.x - 1) amLast = 1;
    }
    __syncthreads();
    if (amLast && threadIdx.x == 0) {
        __threadfence();
        int run = 0;
        for (int b = 0; b < (int)gridDim.x; ++b) { int v = part[b]; part[b] = run; run += v; }
    }
}

__global__ __launch_bounds__(256) void scan_final(const int* __restrict__ deg, const int* __restrict__ part,
                                                  int* __restrict__ offs)
{
    __shared__ int sh[256];
    int i = blockIdx.x * 256 + threadIdx.x;
    int v = (i < NN) ? deg[i] : 0;
    sh[threadIdx.x] = v;
    __syncthreads();
    for (int off = 1; off < 256; off <<= 1) {
        int add = (threadIdx.x >= off) ? sh[threadIdx.x - off] : 0;
        __syncthreads();
        sh[threadIdx.x] += add;
        __syncthreads();
    }
    int excl = sh[threadIdx.x] - v + part[blockIdx.x];
    if (i < NN) offs[i] = excl;
}

// fused: scatter packed edge (src:16 | w:bf16) into slot offs[d]+rank[e] AND master adjacency
__global__ __launch_bounds__(256) void edge_scatter_adj(
    const int* __restrict__ ei, const float* __restrict__ pos,
    const int* __restrict__ offs, const int* __restrict__ rank,
    const int* __restrict__ is_master, const int* __restrict__ inv,
    uint_t* __restrict__ eslot, int* __restrict__ adj_i)
{
    int e = blockIdx.x * 256 + threadIdx.x;
    if (e >= NE) return;
    int s = ei[e];
    int d = ei[NE + e];
    float dx = pos[(size_t)s * 3 + 0] - pos[(size_t)d * 3 + 0];
    float dy = pos[(size_t)s * 3 + 1] - pos[(size_t)d * 3 + 1];
    float dz = pos[(size_t)s * 3 + 2] - pos[(size_t)d * 3 + 2];
    float w = 1.f / (1.f + dx * dx + dy * dy + dz * dz);
    eslot[offs[d] + rank[e]] = (uint_t)s | ((uint_t)f2bf(w) << 16);
    if (is_master[s] && is_master[d]) atomicOr(&adj_i[inv[s] * KS + inv[d]], 1);
}

// one wave per dst node: lane handles dims 2*lane, 2*lane+1; 4-edge unroll + fast silu
__global__ __launch_bounds__(256) void edge_agg(
    const uint_t* __restrict__ eslot, const int* __restrict__ offs, const int* __restrict__ deg,
    const ushort_t* __restrict__ a16, const ushort_t* __restrict__ b16,
    const float* __restrict__ b1, ushort_t* __restrict__ u16, float* __restrict__ cw)
{
    int wid = (blockIdx.x * 256 + threadIdx.x) >> 6;
    int lane = threadIdx.x & 63;
    if (wid >= NN) return;
    int off = offs[wid];
    int n = deg[wid];
    float2 b1v = *(const float2*)(b1 + 2 * lane);
    uint_t bw = ((const uint_t*)(b16 + (size_t)wid * 128))[lane];
    float bf0 = bf2f((ushort_t)(bw & 0xffff)) + b1v.x;
    float bf1 = bf2f((ushort_t)(bw >> 16)) + b1v.y;
    float acc0 = 0.f, acc1 = 0.f, cwa = 0.f;
    int k = 0;
    for (; k + 4 <= n; k += 4) {
        uint_t e0 = eslot[off + k];
        uint_t e1 = eslot[off + k + 1];
        uint_t e2 = eslot[off + k + 2];
        uint_t e3 = eslot[off + k + 3];
        uint_t aw0 = ((const uint_t*)(a16 + (size_t)(e0 & 0xffff) * 128))[lane];
        uint_t aw1 = ((const uint_t*)(a16 + (size_t)(e1 & 0xffff) * 128))[lane];
        uint_t aw2 = ((const uint_t*)(a16 + (size_t)(e2 & 0xffff) * 128))[lane];
        uint_t aw3 = ((const uint_t*)(a16 + (size_t)(e3 & 0xffff) * 128))[lane];
        float w0 = bf2f((ushort_t)(e0 >> 16)), w1 = bf2f((ushort_t)(e1 >> 16));
        float w2 = bf2f((ushort_t)(e2 >> 16)), w3 = bf2f((ushort_t)(e3 >> 16));
        acc0 = fmaf(fsilu(bf2f((ushort_t)(aw0 & 0xffff)) + bf0), w0, acc0);
        acc1 = fmaf(fsilu(bf2f((ushort_t)(aw0 >> 16)) + bf1), w0, acc1);
        acc0 = fmaf(fsilu(bf2f((ushort_t)(aw1 & 0xffff)) + bf0), w1, acc0);
        acc1 = fmaf(fsilu(bf2f((ushort_t)(aw1 >> 16)) + bf1), w1, acc1);
        acc0 = fmaf(fsilu(bf2f((ushort_t)(aw2 & 0xffff)) + bf0), w2, acc0);
        acc1 = fmaf(fsilu(bf2f((ushort_t)(aw2 >> 16)) + bf1), w2, acc1);
        acc0 = fmaf(fsilu(bf2f((ushort_t)(aw3 & 0xffff)) + bf0), w3, acc0);
        acc1 = fmaf(fsilu(bf2f((ushort_t)(aw3 >> 16)) + bf1), w3, acc1);
        cwa += w0 + w1 + w2 + w3;
    }
    for (; k < n; ++k) {
        uint_t e0 = eslot[off + k];
        uint_t aw0 = ((const uint_t*)(a16 + (size_t)(e0 & 0xffff) * 128))[lane];
        float w0 = bf2f((ushort_t)(e0 >> 16));
        acc0 = fmaf(fsilu(bf2f((ushort_t)(aw0 & 0xffff)) + bf0), w0, acc0);
        acc1 = fmaf(fsilu(bf2f((ushort_t)(aw0 >> 16)) + bf1), w0, acc1);
        cwa += w0;
    }
    uint_t packed = (uint_t)f2bf(acc0) | ((uint_t)f2bf(acc1) << 16);
    ((uint_t*)(u16 + (size_t)wid * 128))[lane] = packed;
    if (lane == 0) cw[wid] = cwa;
}

// ============================ master attention ============================
__global__ __launch_bounds__(64) void qk_proj(
    const float* __restrict__ h_m, const float* __restrict__ Wq, const float* __restrict__ Wk,
    float* __restrict__ q, float* __restrict__ kk)
{
    int r = blockIdx.x;
    int t = threadIdx.x;
    __shared__ float hs[64];
    hs[t] = h_m[(size_t)r * 128 + t];
    __syncthreads();
    float aq = 0.f, ak = 0.f;
    for (int s = 0; s < 64; ++s) {
        float hv = hs[s];
        aq = fmaf(hv, Wq[s * 64 + t], aq);
        ak = fmaf(hv, Wk[s * 64 + t], ak);
    }
    q[r * 64 + t] = aq;
    kk[r * 64 + t] = ak;
}

__global__ __launch_bounds__(512) void attn_blend(
    const float* __restrict__ q, const float* __restrict__ kk,
    const int* __restrict__ adj_i, int* __restrict__ B)
{
    int i = blockIdx.x;
    int t = threadIdx.x;
    __shared__ float qi[64];
    __shared__ float red[512];
    if (t < 64) qi[t] = q[i * 64 + t];
    __syncthreads();
    float s = -1e30f;
    if (t < KS) {
        float acc = 0.f;
        for (int c = 0; c < 64; ++c) acc = fmaf(qi[c], kk[t * 64 + c], acc);
        s = acc * 0.125f;
    }
    red[t] = s;
    __syncthreads();
    for (int off = 256; off > 0; off >>= 1) {
        if (t < off) red[t] = fmaxf(red[t], red[t + off]);
        __syncthreads();
    }
    float mx = red[0];
    __syncthreads();
    float e = (t < KS) ? expf(s - mx) : 0.f;
    red[t] = e;
    __syncthreads();
    for (int off = 256; off > 0; off >>= 1) {
        if (t < off) red[t] += red[t + off];
        __syncthreads();
    }
    float denom = red[0];
    if (t < KS) {
        float attn = e / denom;
        float blend = 0.5f * attn + 0.5f * (adj_i[i * KS + t] ? 1.f : 0.f);
        B[i * KS + t] = (blend > (1.f / (float)KS)) && (t != i);
    }
}

// wT[j][i] = (adj[i][j] + w_virtual*vadj[i][j]) / (1 + |pos_i - pos_j|^2)
__global__ __launch_bounds__(256) void wmat_kernel(
    const int* __restrict__ adj_i, const int* __restrict__ B,
    const float* __restrict__ w_virtual, const float* __restrict__ pos_m,
    float* __restrict__ wT)
{
    int idx = blockIdx.x * 256 + threadIdx.x;
    if (idx >= KS * KS) return;
    int j = idx / KS, i = idx % KS;
    int ij = i * KS + j;
    float adjf = adj_i[ij] ? 1.f : 0.f;
    float v = (B[ij] | B[j * KS + i]) ? 1.f : 0.f;
    float aw = adjf + w_virtual[0] * v;
    float dx = pos_m[i * 3 + 0] - pos_m[j * 3 + 0];
    float dy = pos_m[i * 3 + 1] - pos_m[j * 3 + 1];
    float dz = pos_m[i * 3 + 2] - pos_m[j * 3 + 2];
    wT[idx] = aw / (1.f + dx * dx + dy * dy + dz * dz);
}

__global__ __launch_bounds__(64) void cwm_kernel(const float* __restrict__ wT, float* __restrict__ cw_m)
{
    int j = blockIdx.x;
    int lane = threadIdx.x;
    float s = 0.f;
    for (int i = lane; i < KS; i += 64) s += wT[j * KS + i];
    for (int off = 32; off > 0; off >>= 1) s += __shfl_down(s, off);
    if (lane == 0) cw_m[j] = s;
}

// partial[sl][j][t] = sum_{i in slice sl} silu(a_m[i][t] + bf_m[j][t] + b1[t]) * wT[j][i]
__global__ __launch_bounds__(128) void dense_agg(
    const float* __restrict__ a_m, const float* __restrict__ bf_m,
    const float* __restrict__ b1, const float* __restrict__ wT,
    float* __restrict__ partial)
{
    int j = blockIdx.x;
    int sl = blockIdx.y;
    int t = threadIdx.x;
    int i0 = sl * SLICE;
    int i1 = min(KS, i0 + SLICE);
    float bfj = bf_m[(size_t)j * 128 + t] + b1[t];
    float acc = 0.f;
    for (int i = i0; i < i1; ++i) {
        float w = wT[j * KS + i];
        float x = a_m[(size_t)i * 128 + t] + bfj;
        acc = fmaf(fsilu(x), w, acc);
    }
    partial[((size_t)sl * KS + j) * 128 + t] = acc;
}

__global__ __launch_bounds__(128) void master_update(
    const float* __restrict__ h_m, const float* __restrict__ partial, const float* __restrict__ cw_m,
    const float* __restrict__ W2, const float* __restrict__ b2,
    const float* __restrict__ W3, const float* __restrict__ b3, float* __restrict__ h_hier)
{
    int j = blockIdx.x;
    int t = threadIdx.x;
    __shared__ float tsh[128], hsh[128], ash[128];
    float tv = 0.f;
#pragma unroll
    for (int sl = 0; sl < NSL; ++sl) tv += partial[((size_t)sl * KS + j) * 128 + t];
    tsh[t] = tv;
    hsh[t] = h_m[(size_t)j * 128 + t];
    __syncthreads();
    float acc = cw_m[j] * b2[t];
    for (int c = 0; c < 128; ++c) acc = fmaf(tsh[c], W2[c * 128 + t], acc);
    ash[t] = acc;
    __syncthreads();
    float upd = b3[t];
    for (int c = 0; c < 128; ++c) upd = fmaf(hsh[c], W3[c * 128 + t], upd);
    for (int c = 0; c < 128; ++c) upd = fmaf(ash[c], W3[(128 + c) * 128 + t], upd);
    h_hier[(size_t)j * 128 + t] = hsh[t] + upd;
}

__global__ __launch_bounds__(128) void gate_kernel(
    const int* __restrict__ sel, const float* __restrict__ h_global,
    const float* __restrict__ h_hier, const float* __restrict__ Wa1,
    const float* __restrict__ ba1, const float* __restrict__ Wa2,
    const float* __restrict__ ba2, float* __restrict__ out)
{
    int j = blockIdx.x;
    int t = threadIdx.x;
    int node = sel[j];
    __shared__ float x[256];
    __shared__ float g1[128];
    x[t] = h_global[(size_t)node * 128 + t];
    x[128 + t] = h_hier[(size_t)j * 128 + t];
    __syncthreads();
    float acc = ba1[t];
    for (int c = 0; c < 256; ++c) acc = fmaf(x[c], Wa1[c * 128 + t], acc);
    g1[t] = acc / (1.f + expf(-acc));
    __syncthreads();
    float g = ba2[t];
    for (int c = 0; c < 128; ++c) g = fmaf(g1[c], Wa2[c * 128 + t], g);
    out[(size_t)node * 256 + 128 + t] = x[t] + g * x[128 + t];
}

// ============================ launch ============================
extern "C" void kernel_launch(void* const* d_in, const int* in_sizes, int n_in,
                              void* d_out, int out_size, void* d_ws, size_t ws_size,
                              hipStream_t stream)
{
    const float* h        = (const float*)d_in[0];
    const float* h_global = (const float*)d_in[1];
    const float* pos      = (const float*)d_in[2];
    const int*   ei       = (const int*)d_in[3];
    const float* W_a      = (const float*)d_in[5];
    const float* W_b      = (const float*)d_in[6];
    const float* b1       = (const float*)d_in[7];
    const float* W2       = (const float*)d_in[8];
    const float* b2       = (const float*)d_in[9];
    const float* W3       = (const float*)d_in[10];
    const float* b3       = (const float*)d_in[11];
    const float* w_virt   = (const float*)d_in[12];
    const float* Wm1      = (const float*)d_in[13];
    const float* bm1      = (const float*)d_in[14];
    const float* Wm2      = (const float*)d_in[15];
    const float* bm2      = (const float*)d_in[16];
    const float* Wq       = (const float*)d_in[17];
    const float* Wk       = (const float*)d_in[18];
    const float* Wa1      = (const float*)d_in[19];
    const float* ba1      = (const float*)d_in[20];
    const float* Wa2      = (const float*)d_in[21];
    const float* ba2      = (const float*)d_in[22];
    float* out = (float*)d_out;

    // workspace carve
    char* p = (char*)d_ws;
    auto alloc = [&](size_t bytes) -> void* {
        void* q = (void*)p;
        p += (bytes + 255) & ~(size_t)255;
        return q;
    };
    // zeroed region (single memset): deg, is_mast, adj_i, state
    int*   deg      = (int*)alloc((size_t)NN * 4);
    int*   is_mast  = (int*)alloc((size_t)NN * 4);
    int*   adj_i    = (int*)alloc((size_t)KS * KS * 4);
    int*   state    = (int*)alloc(1024 * 4);
    char*  zero_end = p;
    size_t zero_bytes = (size_t)(zero_end - (char*)deg);

    ushort_t* u16   = (ushort_t*)alloc((size_t)NN * 128 * 2);
    float* mscore   = (float*)alloc((size_t)NN * 4);
    float* cw       = (float*)alloc((size_t)NN * 4);
    int*   inv      = (int*)alloc((size_t)NN * 4);
    int*   offs     = (int*)alloc((size_t)NN * 4);
    int*   rank     = (int*)alloc((size_t)NE * 4);
    uint_t* eslot   = (uint_t*)alloc((size_t)NE * 4);
    int*   part     = (int*)alloc(256 * 4);
    int*   sel      = (int*)alloc((size_t)KS * 4);
    float* h_m      = (float*)alloc((size_t)KS * 128 * 4);
    float* pos_m    = (float*)alloc((size_t)KS * 3 * 4);
    float* qm       = (float*)alloc((size_t)KS * 64 * 4);
    float* km       = (float*)alloc((size_t)KS * 64 * 4);
    int*   Bmat     = (int*)alloc((size_t)KS * KS * 4);
    float* wT       = (float*)alloc((size_t)KS * KS * 4);
    float* a_m      = (float*)alloc((size_t)KS * 128 * 4);
    float* bf_m     = (float*)alloc((size_t)KS * 128 * 4);
    float* partial  = (float*)alloc((size_t)NSL * KS * 128 * 4);
    float* cw_m     = (float*)alloc((size_t)KS * 4);
    float* h_hier   = (float*)alloc((size_t)KS * 128 * 4);
    ushort_t* Wta   = (ushort_t*)alloc(128 * 128 * 2);
    ushort_t* Wtb   = (ushort_t*)alloc(128 * 128 * 2);
    ushort_t* Wt3a  = (ushort_t*)alloc(128 * 128 * 2);
    ushort_t* W23t  = (ushort_t*)alloc(128 * 128 * 2);
    float* b23      = (float*)alloc(128 * 4);
    int*   tie_buf  = (int*)alloc(4096 * 4);

    // bf16 a / bf staged in d_out (overwritten later by mfma_local_fused)
    ushort_t* a16 = (ushort_t*)out;
    ushort_t* b16 = a16 + (size_t)NN * 128;

    hipMemsetAsync(deg, 0, zero_bytes, stream);

    const int gemmN64 = (NN + 63) / 64;  // 782
    const int gemmK = (KS + 63) / 64;
    const int g196 = (NN + 255) / 256;   // 196
    const int gE   = (NE + 255) / 256;   // 3125

    // weight prep
    prep_wt<<<dim3(128, 3), 128, 0, stream>>>(W_a, W_b, W3, Wta, Wtb, Wt3a);
    w23t_kernel<<<129, 128, 0, stream>>>(W2, W3, b2, W23t, b23);

    // a = bf16(h@W_a), bf = bf16(h@W_b) via LDS-staged MFMA
    mfma_dual<<<gemmN64, 512, 0, stream>>>(h, Wta, Wtb, a16, b16, NN);

    // CSR degree + rank, then scan (part+top fused)
    deg_hist<<<gE, 256, 0, stream>>>(ei, deg, rank);
    scan_part_fused<<<g196, 256, 0, stream>>>(deg, part, state);
    scan_final<<<g196, 256, 0, stream>>>(deg, part, offs);

    // master scores + 4x8-bit radix top-K (scan fused into hist via last-block)
    score_fused<<<gemmN64, 256, 0, stream>>>(h_global, Wm1, bm1, Wm2, bm2, mscore);
    for (int lvl = 0; lvl < 4; ++lvl)
        hist_fused<<<g196, 256, 0, stream>>>(mscore, state, lvl);
    select_fused<<<g196, 256, 0, stream>>>(mscore, state, sel, tie_buf);
    build_master<<<KS, 128, 0, stream>>>(sel, h_global, pos, is_mast, inv, h_m, pos_m);

    // fused scatter (packed 4B) + master adjacency
    edge_scatter_adj<<<gE, 256, 0, stream>>>(ei, pos, offs, rank, is_mast, inv, eslot, adj_i);

    // gather-side edge aggregation
    edge_agg<<<(NN * 64) / 256, 256, 0, stream>>>(eslot, offs, deg, a16, b16, b1, u16, cw);

    // master attention -> B matrix
    qk_proj<<<KS, 64, 0, stream>>>(h_m, Wq, Wk, qm, km);
    attn_blend<<<KS, 512, 0, stream>>>(qm, km, adj_i, Bmat);

    // fused blend/virtual-adj/distance weight matrix (transposed) + row sums
    wmat_kernel<<<(KS * KS + 255) / 256, 256, 0, stream>>>(adj_i, Bmat, w_virt, pos_m, wT);
    cwm_kernel<<<KS, 64, 0, stream>>>(wT, cw_m);

    // dense backbone on masters
    gemm_dual<<<gemmK, 256, 0, stream>>>(h_m, W_a, W_b, a_m, bf_m, KS, 128);
    dense_agg<<<dim3(KS, NSL), 128, 0, stream>>>(a_m, bf_m, b1, wT, partial);
    master_update<<<KS, 128, 0, stream>>>(h_m, partial, cw_m, W2, b2, W3, b3, h_hier);

    // fused local output
    mfma_local_fused<<<gemmN64, 512, 0, stream>>>(h, u16, Wt3a, W23t, b23, b3, cw,
                                                  h_global, out, NN);

    // overwrite master rows of the global half
    gate_kernel<<<KS, 128, 0, stream>>>(sel, h_global, h_hier, Wa1, ba1, Wa2, ba2, out);
}

// Round 16
// 357.863 us; speedup vs baseline: 1.2168x; 1.2168x over previous
//
#include <hip/hip_runtime.h>
#include <math.h>

#define NN 50000
#define NE 800000
#define KS 500
#define NSL 8
#define SLICE 63

typedef unsigned short ushort_t;
typedef unsigned int uint_t;
typedef short bf16x8 __attribute__((ext_vector_type(8)));
typedef float f32x4 __attribute__((ext_vector_type(4)));

__device__ __forceinline__ float bf2f(ushort_t u) {
    return __uint_as_float(((uint_t)u) << 16);
}
__device__ __forceinline__ ushort_t f2bf(float f) {
    uint_t u = __float_as_uint(f);
    u += 0x7fffu + ((u >> 16) & 1u);   // round-to-nearest-even
    return (ushort_t)(u >> 16);
}
// fast silu: x * rcp(1+exp(-x)) using v_rcp_f32 (~1e-5 rel err) — NOT for the score path
__device__ __forceinline__ float fsilu(float x) {
    return x * __builtin_amdgcn_rcpf(1.f + __expf(-x));
}

// ============================ weight prep ============================
__global__ __launch_bounds__(128) void prep_wt(
    const float* __restrict__ Wa, const float* __restrict__ Wb, const float* __restrict__ W3,
    ushort_t* __restrict__ Wta, ushort_t* __restrict__ Wtb, ushort_t* __restrict__ Wt3a)
{
    int j = blockIdx.x;      // output row = original col
    int k = threadIdx.x;
    int y = blockIdx.y;
    const float* src = (y == 0) ? Wa : (y == 1) ? Wb : W3;
    ushort_t* dst = (y == 0) ? Wta : (y == 1) ? Wtb : Wt3a;
    dst[j * 128 + k] = f2bf(src[k * 128 + j]);
}

// W23t[j][c] = bf16(sum_k W2[c][k]*W3[128+k][j]); block 128 does b23[j]
__global__ __launch_bounds__(128) void w23t_kernel(
    const float* __restrict__ W2, const float* __restrict__ W3, const float* __restrict__ b2,
    ushort_t* __restrict__ W23t, float* __restrict__ b23)
{
    int c = blockIdx.x;
    int j = threadIdx.x;
    if (c < 128) {
        float acc = 0.f;
        for (int k = 0; k < 128; ++k) acc = fmaf(W2[c * 128 + k], W3[(128 + k) * 128 + j], acc);
        W23t[j * 128 + c] = f2bf(acc);
    } else {
        float acc = 0.f;
        for (int k = 0; k < 128; ++k) acc = fmaf(b2[k], W3[(128 + k) * 128 + j], acc);
        b23[j] = acc;
    }
}

// ============================ MFMA GEMM kernels ============================
// a16 = bf16(h@W_a), b16 = bf16(h@W_b). A-tile + per-kk weight K-slices staged in LDS.
__global__ __launch_bounds__(512) void mfma_dual(
    const float* __restrict__ h, const ushort_t* __restrict__ Wta, const ushort_t* __restrict__ Wtb,
    ushort_t* __restrict__ C1, ushort_t* __restrict__ C2, int M)
{
    __shared__ ushort_t As[64][136];
    __shared__ ushort_t Wa_s[128][40];
    __shared__ ushort_t Wb_s[128][40];
    const int t = threadIdx.x;
    const int bm = blockIdx.x * 64;
    for (int idx = t * 4; idx < 64 * 128; idx += 2048) {
        int r = idx >> 7, c = idx & 127;
        int gr = bm + r;
        float4 v = make_float4(0.f, 0.f, 0.f, 0.f);
        if (gr < M) v = *(const float4*)(h + (size_t)gr * 128 + c);
        As[r][c + 0] = f2bf(v.x); As[r][c + 1] = f2bf(v.y);
        As[r][c + 2] = f2bf(v.z); As[r][c + 3] = f2bf(v.w);
    }
    const int w = t >> 6;
    const int lane = t & 63;
    const int rowgrp = w >> 1;
    const int mat = w & 1;
    const int i = lane & 15, g = lane >> 4;
    const int row = rowgrp * 16 + i;
    const ushort_t* wsrc = (t < 256) ? Wta : Wtb;
    ushort_t* wdst0 = (t < 256) ? &Wa_s[0][0] : &Wb_s[0][0];
    const int tt = t & 255;
    const int wr = tt >> 1, wc = (tt & 1) * 16;

    f32x4 acc[8];
#pragma unroll
    for (int n = 0; n < 8; ++n) acc[n] = (f32x4)0.f;

#pragma unroll
    for (int kk = 0; kk < 4; ++kk) {
        __syncthreads();
        {
            uint4 v0 = *(const uint4*)(wsrc + (size_t)wr * 128 + kk * 32 + wc);
            uint4 v1 = *(const uint4*)(wsrc + (size_t)wr * 128 + kk * 32 + wc + 8);
            *(uint4*)(wdst0 + wr * 40 + wc) = v0;
            *(uint4*)(wdst0 + wr * 40 + wc + 8) = v1;
        }
        __syncthreads();
        const ushort_t* Ws = mat ? &Wb_s[0][0] : &Wa_s[0][0];
        bf16x8 af = *(const bf16x8*)(&As[row][kk * 32 + g * 8]);
#pragma unroll
        for (int n = 0; n < 8; ++n) {
            bf16x8 bf = *(const bf16x8*)(Ws + (n * 16 + i) * 40 + g * 8);
            acc[n] = __builtin_amdgcn_mfma_f32_16x16x32_bf16(af, bf, acc[n], 0, 0, 0);
        }
    }
    ushort_t* C = mat ? C2 : C1;
    const int R = bm + rowgrp * 16;
#pragma unroll
    for (int n = 0; n < 8; ++n) {
        int col = n * 16 + i;
#pragma unroll
        for (int v = 0; v < 4; ++v) {
            int orow = R + 4 * g + v;
            if (orow < M) C[(size_t)orow * 128 + col] = f2bf(acc[n][v]);
        }
    }
}

// out[:,0:128] = h + h@W3a + u16@W23 + cw*b23 + b3 ; out[:,128:256] = h_global
__global__ __launch_bounds__(512) void mfma_local_fused(
    const float* __restrict__ h, const ushort_t* __restrict__ u16,
    const ushort_t* __restrict__ Wt3a, const ushort_t* __restrict__ W23t,
    const float* __restrict__ b23, const float* __restrict__ b3,
    const float* __restrict__ cw, const float* __restrict__ h_global,
    float* __restrict__ out, int M)
{
    __shared__ ushort_t Hs[64][136];
    __shared__ ushort_t Us[64][136];
    __shared__ ushort_t W3s[128][40];
    __shared__ ushort_t W2s[128][40];
    const int t = threadIdx.x;
    const int bm = blockIdx.x * 64;
    for (int idx = t * 4; idx < 64 * 128; idx += 2048) {
        int r = idx >> 7, c = idx & 127;
        int gr = bm + r;
        float4 v = make_float4(0.f, 0.f, 0.f, 0.f);
        uint2 uv = make_uint2(0, 0);
        if (gr < M) {
            v = *(const float4*)(h + (size_t)gr * 128 + c);
            uv = *(const uint2*)(u16 + (size_t)gr * 128 + c);
            float4 hgv = *(const float4*)(h_global + (size_t)gr * 128 + c);
            *(float4*)(out + (size_t)gr * 256 + 128 + c) = hgv;   // global-half copy
        }
        Hs[r][c + 0] = f2bf(v.x); Hs[r][c + 1] = f2bf(v.y);
        Hs[r][c + 2] = f2bf(v.z); Hs[r][c + 3] = f2bf(v.w);
        Us[r][c + 0] = (ushort_t)(uv.x & 0xffff); Us[r][c + 1] = (ushort_t)(uv.x >> 16);
        Us[r][c + 2] = (ushort_t)(uv.y & 0xffff); Us[r][c + 3] = (ushort_t)(uv.y >> 16);
    }
    const int w = t >> 6;
    const int lane = t & 63;
    const int rowgrp = w >> 1;
    const int nb = (w & 1) * 4;
    const int i = lane & 15, g = lane >> 4;
    const int row = rowgrp * 16 + i;
    const ushort_t* wsrc = (t < 256) ? Wt3a : W23t;
    ushort_t* wdst0 = (t < 256) ? &W3s[0][0] : &W2s[0][0];
    const int tt = t & 255;
    const int wr = tt >> 1, wc = (tt & 1) * 16;

    f32x4 acc[4];
#pragma unroll
    for (int n = 0; n < 4; ++n) acc[n] = (f32x4)0.f;

#pragma unroll
    for (int kk = 0; kk < 4; ++kk) {
        __syncthreads();
        {
            uint4 v0 = *(const uint4*)(wsrc + (size_t)wr * 128 + kk * 32 + wc);
            uint4 v1 = *(const uint4*)(wsrc + (size_t)wr * 128 + kk * 32 + wc + 8);
            *(uint4*)(wdst0 + wr * 40 + wc) = v0;
            *(uint4*)(wdst0 + wr * 40 + wc + 8) = v1;
        }
        __syncthreads();
        bf16x8 aH = *(const bf16x8*)(&Hs[row][kk * 32 + g * 8]);
        bf16x8 aU = *(const bf16x8*)(&Us[row][kk * 32 + g * 8]);
#pragma unroll
        for (int n = 0; n < 4; ++n) {
            bf16x8 b3f = *(const bf16x8*)(&W3s[(nb + n) * 16 + i][g * 8]);
            bf16x8 b2f = *(const bf16x8*)(&W2s[(nb + n) * 16 + i][g * 8]);
            acc[n] = __builtin_amdgcn_mfma_f32_16x16x32_bf16(aH, b3f, acc[n], 0, 0, 0);
            acc[n] = __builtin_amdgcn_mfma_f32_16x16x32_bf16(aU, b2f, acc[n], 0, 0, 0);
        }
    }
    const int R = bm + rowgrp * 16;
    float cwv[4];
#pragma unroll
    for (int v = 0; v < 4; ++v) {
        int orow = R + 4 * g + v;
        cwv[v] = (orow < M) ? cw[orow] : 0.f;
    }
#pragma unroll
    for (int n = 0; n < 4; ++n) {
        int col = (nb + n) * 16 + i;
        float b3v = b3[col];
        float b23v = b23[col];
#pragma unroll
        for (int v = 0; v < 4; ++v) {
            int orow = R + 4 * g + v;
            if (orow < M) {
                float res = bf2f(Hs[rowgrp * 16 + 4 * g + v][col]);
                out[(size_t)orow * 256 + col] = acc[n][v] + b3v + cwv[v] * b23v + res;
            }
        }
    }
}

// fused fp32 score: mout = sigmoid(silu(hs@Wm1 + bm1)@Wm2 + bm2), hs = h_global[:, 0:64]
__global__ __launch_bounds__(256) void score_fused(
    const float* __restrict__ h_global, const float* __restrict__ Wm1,
    const float* __restrict__ bm1, const float* __restrict__ Wm2,
    const float* __restrict__ bm2, float* __restrict__ mout)
{
    __shared__ float Hs[64][64];
    const int t = threadIdx.x;
    const int bm = blockIdx.x * 64;
    for (int idx = t * 4; idx < 64 * 64; idx += 1024) {
        int r = idx >> 6, c = idx & 63;
        int gr = bm + r;
        float4 v = make_float4(0.f, 0.f, 0.f, 0.f);
        if (gr < NN) v = *(const float4*)(h_global + (size_t)gr * 128 + c);
        *(float4*)(&Hs[r][c]) = v;
    }
    __syncthreads();
    const int col = (t & 31) * 4;
    const int r0 = (t >> 5) * 8;
    float4 bmv = *(const float4*)(bm1 + col);
    float4 acc[8];
#pragma unroll
    for (int r = 0; r < 8; ++r) acc[r] = bmv;
    for (int k = 0; k < 64; ++k) {
        float4 w = *(const float4*)(Wm1 + k * 128 + col);
#pragma unroll
        for (int r = 0; r < 8; ++r) {
            float av = Hs[r0 + r][k];
            acc[r].x = fmaf(av, w.x, acc[r].x);
            acc[r].y = fmaf(av, w.y, acc[r].y);
            acc[r].z = fmaf(av, w.z, acc[r].z);
            acc[r].w = fmaf(av, w.w, acc[r].w);
        }
    }
    float4 w2v = *(const float4*)(Wm2 + col);
    float pr[8];
#pragma unroll
    for (int r = 0; r < 8; ++r) {
        float s = 0.f;
        s = fmaf(acc[r].x / (1.f + expf(-acc[r].x)), w2v.x, s);
        s = fmaf(acc[r].y / (1.f + expf(-acc[r].y)), w2v.y, s);
        s = fmaf(acc[r].z / (1.f + expf(-acc[r].z)), w2v.z, s);
        s = fmaf(acc[r].w / (1.f + expf(-acc[r].w)), w2v.w, s);
        pr[r] = s;
    }
#pragma unroll
    for (int off = 1; off < 32; off <<= 1) {
#pragma unroll
        for (int r = 0; r < 8; ++r) pr[r] += __shfl_xor(pr[r], off, 64);
    }
    if ((t & 31) == 0) {
        float bm2v = bm2[0];
#pragma unroll
        for (int r = 0; r < 8; ++r) {
            int gr = bm + r0 + r;
            if (gr < NN) mout[gr] = 1.f / (1.f + expf(-(pr[r] + bm2v)));
        }
    }
}

// f32 VALU gemm for the small master pass (KS=500)
__global__ __launch_bounds__(256) void gemm_dual(
    const float* __restrict__ A, const float* __restrict__ W1, const float* __restrict__ W2,
    float* __restrict__ C1, float* __restrict__ C2, int M, int ldc)
{
    __shared__ float As[64][128];
    const int t = threadIdx.x;
    const int bm = blockIdx.x * 64;
    for (int idx = t * 4; idx < 64 * 128; idx += 1024) {
        int r = idx >> 7, c = idx & 127;
        int gr = bm + r;
        float4 v = make_float4(0.f, 0.f, 0.f, 0.f);
        if (gr < M) v = *(const float4*)(A + (size_t)gr * 128 + c);
        *(float4*)(&As[r][c]) = v;
    }
    __syncthreads();
    const int col = (t & 31) * 4;
    const int r0 = (t >> 5) * 8;
    float4 acc1[8], acc2[8];
#pragma unroll
    for (int r = 0; r < 8; ++r) { acc1[r] = make_float4(0,0,0,0); acc2[r] = make_float4(0,0,0,0); }
    for (int k = 0; k < 128; ++k) {
        float4 w1 = *(const float4*)(W1 + k * 128 + col);
        float4 w2 = *(const float4*)(W2 + k * 128 + col);
#pragma unroll
        for (int r = 0; r < 8; ++r) {
            float av = As[r0 + r][k];
            acc1[r].x = fmaf(av, w1.x, acc1[r].x);
            acc1[r].y = fmaf(av, w1.y, acc1[r].y);
            acc1[r].z = fmaf(av, w1.z, acc1[r].z);
            acc1[r].w = fmaf(av, w1.w, acc1[r].w);
            acc2[r].x = fmaf(av, w2.x, acc2[r].x);
            acc2[r].y = fmaf(av, w2.y, acc2[r].y);
            acc2[r].z = fmaf(av, w2.z, acc2[r].z);
            acc2[r].w = fmaf(av, w2.w, acc2[r].w);
        }
    }
#pragma unroll
    for (int r = 0; r < 8; ++r) {
        int gr = bm + r0 + r;
        if (gr < M) {
            *(float4*)(C1 + (size_t)gr * ldc + col) = acc1[r];
            *(float4*)(C2 + (size_t)gr * ldc + col) = acc2[r];
        }
    }
}

// ============================ top-K (4x8-bit radix, LDS-privatized) ============================
// state layout: [0..255] bins, [256] prefix, [257] remaining, [258] gt counter, [259] tie counter
__global__ __launch_bounds__(256) void hist_pass(const float* __restrict__ m, int* state, int level)
{
    __shared__ int lh[256];
    lh[threadIdx.x] = 0;
    __syncthreads();
    int i = blockIdx.x * 256 + threadIdx.x;
    if (i == 0 && level == 0) state[257] = KS;
    if (i < NN) {
        unsigned v = __float_as_uint(m[i]);
        unsigned prefix = (unsigned)state[256];
        int shift = 32 - 8 * level;
        bool ok = (level == 0) || ((v >> shift) == prefix);
        if (ok) {
            unsigned byte = (v >> (shift - 8)) & 255u;
            atomicAdd(&lh[byte], 1);
        }
    }
    __syncthreads();
    if (lh[threadIdx.x]) atomicAdd(&state[threadIdx.x], lh[threadIdx.x]);
}

__global__ void hist_scan(int* state)
{
    int remaining = state[257];
    int cum = 0, bin = 0;
    for (int b = 255; b >= 0; --b) {
        int c = state[b];
        if (cum + c >= remaining) { bin = b; remaining -= cum; break; }
        cum += c;
    }
    state[256] = (int)(((unsigned)state[256] << 8) | (unsigned)bin);
    state[257] = remaining;
    for (int b = 0; b < 256; ++b) state[b] = 0;
}

__global__ __launch_bounds__(256) void select_topk(const float* __restrict__ m, int* state,
                                                   int* sel, int* tie_buf)
{
    int i = blockIdx.x * 256 + threadIdx.x;
    if (i >= NN) return;
    unsigned v = __float_as_uint(m[i]);
    unsigned T = (unsigned)state[256];
    if (v > T) {
        int p = atomicAdd(&state[258], 1);
        sel[p] = i;
    } else if (v == T) {
        int p = atomicAdd(&state[259], 1);
        if (p < 4096) tie_buf[p] = i;
    }
}

__global__ __launch_bounds__(256) void tie_resolve(int* state, int* sel, const int* tie_buf)
{
    int need = state[257];
    int cgt = state[258];
    int tcount = state[259];
    if (tcount > 4096) tcount = 4096;
    for (int t = threadIdx.x; t < tcount; t += blockDim.x) {
        int id = tie_buf[t];
        int rank = 0;
        for (int u = 0; u < tcount; ++u) rank += (tie_buf[u] < id);
        if (rank < need) sel[cgt + rank] = id;
    }
}

__global__ __launch_bounds__(128) void build_master(
    const int* __restrict__ sel, const float* __restrict__ h_global,
    const float* __restrict__ pos, int* __restrict__ is_master, int* __restrict__ inv,
    float* __restrict__ h_m, float* __restrict__ pos_m)
{
    int r = blockIdx.x;
    int t = threadIdx.x;
    int node = sel[r];
    if (t == 0) {
        is_master[node] = 1;
        inv[node] = r;
        pos_m[r * 3 + 0] = pos[(size_t)node * 3 + 0];
        pos_m[r * 3 + 1] = pos[(size_t)node * 3 + 1];
        pos_m[r * 3 + 2] = pos[(size_t)node * 3 + 2];
    }
    h_m[(size_t)r * 128 + t] = h_global[(size_t)node * 128 + t];
}

// ============================ CSR build (group edges by dst) ============================
__global__ __launch_bounds__(256) void deg_hist(const int* __restrict__ ei, int* __restrict__ deg,
                                                int* __restrict__ rank)
{
    int e = blockIdx.x * 256 + threadIdx.x;
    if (e < NE) rank[e] = atomicAdd(&deg[ei[NE + e]], 1);
}

__global__ __launch_bounds__(256) void scan_part(const int* __restrict__ deg, int* __restrict__ part)
{
    __shared__ int red[256];
    int i = blockIdx.x * 256 + threadIdx.x;
    red[threadIdx.x] = (i < NN) ? deg[i] : 0;
    __syncthreads();
    for (int off = 128; off > 0; off >>= 1) {
        if (threadIdx.x < off) red[threadIdx.x] += red[threadIdx.x + off];
        __syncthreads();
    }
    if (threadIdx.x == 0) part[blockIdx.x] = red[0];
}

__global__ void scan_top(int* part, int np)
{
    if (threadIdx.x == 0) {
        int run = 0;
        for (int i = 0; i < np; ++i) { int v = part[i]; part[i] = run; run += v; }
    }
}

__global__ __launch_bounds__(256) void scan_final(const int* __restrict__ deg, const int* __restrict__ part,
                                                  int* __restrict__ offs)
{
    __shared__ int sh[256];
    int i = blockIdx.x * 256 + threadIdx.x;
    int v = (i < NN) ? deg[i] : 0;
    sh[threadIdx.x] = v;
    __syncthreads();
    for (int off = 1; off < 256; off <<= 1) {
        int add = (threadIdx.x >= off) ? sh[threadIdx.x - off] : 0;
        __syncthreads();
        sh[threadIdx.x] += add;
        __syncthreads();
    }
    int excl = sh[threadIdx.x] - v + part[blockIdx.x];
    if (i < NN) offs[i] = excl;
}

// fused: scatter packed edge (src:16 | w:bf16) into slot offs[d]+rank[e] AND master adjacency
__global__ __launch_bounds__(256) void edge_scatter_adj(
    const int* __restrict__ ei, const float* __restrict__ pos,
    const int* __restrict__ offs, const int* __restrict__ rank,
    const int* __restrict__ is_master, const int* __restrict__ inv,
    uint_t* __restrict__ eslot, int* __restrict__ adj_i)
{
    int e = blockIdx.x * 256 + threadIdx.x;
    if (e >= NE) return;
    int s = ei[e];
    int d = ei[NE + e];
    float dx = pos[(size_t)s * 3 + 0] - pos[(size_t)d * 3 + 0];
    float dy = pos[(size_t)s * 3 + 1] - pos[(size_t)d * 3 + 1];
    float dz = pos[(size_t)s * 3 + 2] - pos[(size_t)d * 3 + 2];
    float w = 1.f / (1.f + dx * dx + dy * dy + dz * dz);
    eslot[offs[d] + rank[e]] = (uint_t)s | ((uint_t)f2bf(w) << 16);
    if (is_master[s] && is_master[d]) atomicOr(&adj_i[inv[s] * KS + inv[d]], 1);
}

// one wave per dst node: lane handles dims 2*lane, 2*lane+1; 4-edge unroll + fast silu
__global__ __launch_bounds__(256) void edge_agg(
    const uint_t* __restrict__ eslot, const int* __restrict__ offs, const int* __restrict__ deg,
    const ushort_t* __restrict__ a16, const ushort_t* __restrict__ b16,
    const float* __restrict__ b1, ushort_t* __restrict__ u16, float* __restrict__ cw)
{
    int wid = (blockIdx.x * 256 + threadIdx.x) >> 6;
    int lane = threadIdx.x & 63;
    if (wid >= NN) return;
    int off = offs[wid];
    int n = deg[wid];
    float2 b1v = *(const float2*)(b1 + 2 * lane);
    uint_t bw = ((const uint_t*)(b16 + (size_t)wid * 128))[lane];
    float bf0 = bf2f((ushort_t)(bw & 0xffff)) + b1v.x;
    float bf1 = bf2f((ushort_t)(bw >> 16)) + b1v.y;
    float acc0 = 0.f, acc1 = 0.f, cwa = 0.f;
    int k = 0;
    for (; k + 4 <= n; k += 4) {
        uint_t e0 = eslot[off + k];
        uint_t e1 = eslot[off + k + 1];
        uint_t e2 = eslot[off + k + 2];
        uint_t e3 = eslot[off + k + 3];
        uint_t aw0 = ((const uint_t*)(a16 + (size_t)(e0 & 0xffff) * 128))[lane];
        uint_t aw1 = ((const uint_t*)(a16 + (size_t)(e1 & 0xffff) * 128))[lane];
        uint_t aw2 = ((const uint_t*)(a16 + (size_t)(e2 & 0xffff) * 128))[lane];
        uint_t aw3 = ((const uint_t*)(a16 + (size_t)(e3 & 0xffff) * 128))[lane];
        float w0 = bf2f((ushort_t)(e0 >> 16)), w1 = bf2f((ushort_t)(e1 >> 16));
        float w2 = bf2f((ushort_t)(e2 >> 16)), w3 = bf2f((ushort_t)(e3 >> 16));
        acc0 = fmaf(fsilu(bf2f((ushort_t)(aw0 & 0xffff)) + bf0), w0, acc0);
        acc1 = fmaf(fsilu(bf2f((ushort_t)(aw0 >> 16)) + bf1), w0, acc1);
        acc0 = fmaf(fsilu(bf2f((ushort_t)(aw1 & 0xffff)) + bf0), w1, acc0);
        acc1 = fmaf(fsilu(bf2f((ushort_t)(aw1 >> 16)) + bf1), w1, acc1);
        acc0 = fmaf(fsilu(bf2f((ushort_t)(aw2 & 0xffff)) + bf0), w2, acc0);
        acc1 = fmaf(fsilu(bf2f((ushort_t)(aw2 >> 16)) + bf1), w2, acc1);
        acc0 = fmaf(fsilu(bf2f((ushort_t)(aw3 & 0xffff)) + bf0), w3, acc0);
        acc1 = fmaf(fsilu(bf2f((ushort_t)(aw3 >> 16)) + bf1), w3, acc1);
        cwa += w0 + w1 + w2 + w3;
    }
    for (; k < n; ++k) {
        uint_t e0 = eslot[off + k];
        uint_t aw0 = ((const uint_t*)(a16 + (size_t)(e0 & 0xffff) * 128))[lane];
        float w0 = bf2f((ushort_t)(e0 >> 16));
        acc0 = fmaf(fsilu(bf2f((ushort_t)(aw0 & 0xffff)) + bf0), w0, acc0);
        acc1 = fmaf(fsilu(bf2f((ushort_t)(aw0 >> 16)) + bf1), w0, acc1);
        cwa += w0;
    }
    uint_t packed = (uint_t)f2bf(acc0) | ((uint_t)f2bf(acc1) << 16);
    ((uint_t*)(u16 + (size_t)wid * 128))[lane] = packed;
    if (lane == 0) cw[wid] = cwa;
}

// ============================ master attention ============================
__global__ __launch_bounds__(64) void qk_proj(
    const float* __restrict__ h_m, const float* __restrict__ Wq, const float* __restrict__ Wk,
    float* __restrict__ q, float* __restrict__ kk)
{
    int r = blockIdx.x;
    int t = threadIdx.x;
    __shared__ float hs[64];
    hs[t] = h_m[(size_t)r * 128 + t];
    __syncthreads();
    float aq = 0.f, ak = 0.f;
    for (int s = 0; s < 64; ++s) {
        float hv = hs[s];
        aq = fmaf(hv, Wq[s * 64 + t], aq);
        ak = fmaf(hv, Wk[s * 64 + t], ak);
    }
    q[r * 64 + t] = aq;
    kk[r * 64 + t] = ak;
}

__global__ __launch_bounds__(512) void attn_blend(
    const float* __restrict__ q, const float* __restrict__ kk,
    const int* __restrict__ adj_i, int* __restrict__ B)
{
    int i = blockIdx.x;
    int t = threadIdx.x;
    __shared__ float qi[64];
    __shared__ float red[512];
    if (t < 64) qi[t] = q[i * 64 + t];
    __syncthreads();
    float s = -1e30f;
    if (t < KS) {
        float acc = 0.f;
        for (int c = 0; c < 64; ++c) acc = fmaf(qi[c], kk[t * 64 + c], acc);
        s = acc * 0.125f;
    }
    red[t] = s;
    __syncthreads();
    for (int off = 256; off > 0; off >>= 1) {
        if (t < off) red[t] = fmaxf(red[t], red[t + off]);
        __syncthreads();
    }
    float mx = red[0];
    __syncthreads();
    float e = (t < KS) ? expf(s - mx) : 0.f;
    red[t] = e;
    __syncthreads();
    for (int off = 256; off > 0; off >>= 1) {
        if (t < off) red[t] += red[t + off];
        __syncthreads();
    }
    float denom = red[0];
    if (t < KS) {
        float attn = e / denom;
        float blend = 0.5f * attn + 0.5f * (adj_i[i * KS + t] ? 1.f : 0.f);
        B[i * KS + t] = (blend > (1.f / (float)KS)) && (t != i);
    }
}

// wT[j][i] = (adj[i][j] + w_virtual*vadj[i][j]) / (1 + |pos_i - pos_j|^2)
__global__ __launch_bounds__(256) void wmat_kernel(
    const int* __restrict__ adj_i, const int* __restrict__ B,
    const float* __restrict__ w_virtual, const float* __restrict__ pos_m,
    float* __restrict__ wT)
{
    int idx = blockIdx.x * 256 + threadIdx.x;
    if (idx >= KS * KS) return;
    int j = idx / KS, i = idx % KS;
    int ij = i * KS + j;
    float adjf = adj_i[ij] ? 1.f : 0.f;
    float v = (B[ij] | B[j * KS + i]) ? 1.f : 0.f;
    float aw = adjf + w_virtual[0] * v;
    float dx = pos_m[i * 3 + 0] - pos_m[j * 3 + 0];
    float dy = pos_m[i * 3 + 1] - pos_m[j * 3 + 1];
    float dz = pos_m[i * 3 + 2] - pos_m[j * 3 + 2];
    wT[idx] = aw / (1.f + dx * dx + dy * dy + dz * dz);
}

__global__ __launch_bounds__(64) void cwm_kernel(const float* __restrict__ wT, float* __restrict__ cw_m)
{
    int j = blockIdx.x;
    int lane = threadIdx.x;
    float s = 0.f;
    for (int i = lane; i < KS; i += 64) s += wT[j * KS + i];
    for (int off = 32; off > 0; off >>= 1) s += __shfl_down(s, off);
    if (lane == 0) cw_m[j] = s;
}

// partial[sl][j][t] = sum_{i in slice sl} silu(a_m[i][t] + bf_m[j][t] + b1[t]) * wT[j][i]
__global__ __launch_bounds__(128) void dense_agg(
    const float* __restrict__ a_m, const float* __restrict__ bf_m,
    const float* __restrict__ b1, const float* __restrict__ wT,
    float* __restrict__ partial)
{
    int j = blockIdx.x;
    int sl = blockIdx.y;
    int t = threadIdx.x;
    int i0 = sl * SLICE;
    int i1 = min(KS, i0 + SLICE);
    float bfj = bf_m[(size_t)j * 128 + t] + b1[t];
    float acc = 0.f;
    for (int i = i0; i < i1; ++i) {
        float w = wT[j * KS + i];
        float x = a_m[(size_t)i * 128 + t] + bfj;
        acc = fmaf(fsilu(x), w, acc);
    }
    partial[((size_t)sl * KS + j) * 128 + t] = acc;
}

__global__ __launch_bounds__(128) void master_update(
    const float* __restrict__ h_m, const float* __restrict__ partial, const float* __restrict__ cw_m,
    const float* __restrict__ W2, const float* __restrict__ b2,
    const float* __restrict__ W3, const float* __restrict__ b3, float* __restrict__ h_hier)
{
    int j = blockIdx.x;
    int t = threadIdx.x;
    __shared__ float tsh[128], hsh[128], ash[128];
    float tv = 0.f;
#pragma unroll
    for (int sl = 0; sl < NSL; ++sl) tv += partial[((size_t)sl * KS + j) * 128 + t];
    tsh[t] = tv;
    hsh[t] = h_m[(size_t)j * 128 + t];
    __syncthreads();
    float acc = cw_m[j] * b2[t];
    for (int c = 0; c < 128; ++c) acc = fmaf(tsh[c], W2[c * 128 + t], acc);
    ash[t] = acc;
    __syncthreads();
    float upd = b3[t];
    for (int c = 0; c < 128; ++c) upd = fmaf(hsh[c], W3[c * 128 + t], upd);
    for (int c = 0; c < 128; ++c) upd = fmaf(ash[c], W3[(128 + c) * 128 + t], upd);
    h_hier[(size_t)j * 128 + t] = hsh[t] + upd;
}

__global__ __launch_bounds__(128) void gate_kernel(
    const int* __restrict__ sel, const float* __restrict__ h_global,
    const float* __restrict__ h_hier, const float* __restrict__ Wa1,
    const float* __restrict__ ba1, const float* __restrict__ Wa2,
    const float* __restrict__ ba2, float* __restrict__ out)
{
    int j = blockIdx.x;
    int t = threadIdx.x;
    int node = sel[j];
    __shared__ float x[256];
    __shared__ float g1[128];
    x[t] = h_global[(size_t)node * 128 + t];
    x[128 + t] = h_hier[(size_t)j * 128 + t];
    __syncthreads();
    float acc = ba1[t];
    for (int c = 0; c < 256; ++c) acc = fmaf(x[c], Wa1[c * 128 + t], acc);
    g1[t] = acc / (1.f + expf(-acc));
    __syncthreads();
    float g = ba2[t];
    for (int c = 0; c < 128; ++c) g = fmaf(g1[c], Wa2[c * 128 + t], g);
    out[(size_t)node * 256 + 128 + t] = x[t] + g * x[128 + t];
}

// ============================ launch ============================
extern "C" void kernel_launch(void* const* d_in, const int* in_sizes, int n_in,
                              void* d_out, int out_size, void* d_ws, size_t ws_size,
                              hipStream_t stream)
{
    const float* h        = (const float*)d_in[0];
    const float* h_global = (const float*)d_in[1];
    const float* pos      = (const float*)d_in[2];
    const int*   ei       = (const int*)d_in[3];
    const float* W_a      = (const float*)d_in[5];
    const float* W_b      = (const float*)d_in[6];
    const float* b1       = (const float*)d_in[7];
    const float* W2       = (const float*)d_in[8];
    const float* b2       = (const float*)d_in[9];
    const float* W3       = (const float*)d_in[10];
    const float* b3       = (const float*)d_in[11];
    const float* w_virt   = (const float*)d_in[12];
    const float* Wm1      = (const float*)d_in[13];
    const float* bm1      = (const float*)d_in[14];
    const float* Wm2      = (const float*)d_in[15];
    const float* bm2      = (const float*)d_in[16];
    const float* Wq       = (const float*)d_in[17];
    const float* Wk       = (const float*)d_in[18];
    const float* Wa1      = (const float*)d_in[19];
    const float* ba1      = (const float*)d_in[20];
    const float* Wa2      = (const float*)d_in[21];
    const float* ba2      = (const float*)d_in[22];
    float* out = (float*)d_out;

    // workspace carve
    char* p = (char*)d_ws;
    auto alloc = [&](size_t bytes) -> void* {
        void* q = (void*)p;
        p += (bytes + 255) & ~(size_t)255;
        return q;
    };
    // zeroed region (single memset): deg, is_mast, adj_i, state
    int*   deg      = (int*)alloc((size_t)NN * 4);
    int*   is_mast  = (int*)alloc((size_t)NN * 4);
    int*   adj_i    = (int*)alloc((size_t)KS * KS * 4);
    int*   state    = (int*)alloc(1024 * 4);
    char*  zero_end = p;
    size_t zero_bytes = (size_t)(zero_end - (char*)deg);

    ushort_t* u16   = (ushort_t*)alloc((size_t)NN * 128 * 2);
    float* mscore   = (float*)alloc((size_t)NN * 4);
    float* cw       = (float*)alloc((size_t)NN * 4);
    int*   inv      = (int*)alloc((size_t)NN * 4);
    int*   offs     = (int*)alloc((size_t)NN * 4);
    int*   rank     = (int*)alloc((size_t)NE * 4);
    uint_t* eslot   = (uint_t*)alloc((size_t)NE * 4);
    int*   part     = (int*)alloc(256 * 4);
    int*   sel      = (int*)alloc((size_t)KS * 4);
    float* h_m      = (float*)alloc((size_t)KS * 128 * 4);
    float* pos_m    = (float*)alloc((size_t)KS * 3 * 4);
    float* qm       = (float*)alloc((size_t)KS * 64 * 4);
    float* km       = (float*)alloc((size_t)KS * 64 * 4);
    int*   Bmat     = (int*)alloc((size_t)KS * KS * 4);
    float* wT       = (float*)alloc((size_t)KS * KS * 4);
    float* a_m      = (float*)alloc((size_t)KS * 128 * 4);
    float* bf_m     = (float*)alloc((size_t)KS * 128 * 4);
    float* partial  = (float*)alloc((size_t)NSL * KS * 128 * 4);
    float* cw_m     = (float*)alloc((size_t)KS * 4);
    float* h_hier   = (float*)alloc((size_t)KS * 128 * 4);
    ushort_t* Wta   = (ushort_t*)alloc(128 * 128 * 2);
    ushort_t* Wtb   = (ushort_t*)alloc(128 * 128 * 2);
    ushort_t* Wt3a  = (ushort_t*)alloc(128 * 128 * 2);
    ushort_t* W23t  = (ushort_t*)alloc(128 * 128 * 2);
    float* b23      = (float*)alloc(128 * 4);
    int*   tie_buf  = (int*)alloc(4096 * 4);

    // bf16 a / bf staged in d_out (overwritten later by mfma_local_fused)
    ushort_t* a16 = (ushort_t*)out;
    ushort_t* b16 = a16 + (size_t)NN * 128;

    hipMemsetAsync(deg, 0, zero_bytes, stream);

    const int gemmN64 = (NN + 63) / 64;  // 782
    const int gemmK = (KS + 63) / 64;
    const int g196 = (NN + 255) / 256;   // 196
    const int gE   = (NE + 255) / 256;   // 3125

    // weight prep
    prep_wt<<<dim3(128, 3), 128, 0, stream>>>(W_a, W_b, W3, Wta, Wtb, Wt3a);
    w23t_kernel<<<129, 128, 0, stream>>>(W2, W3, b2, W23t, b23);

    // a = bf16(h@W_a), bf = bf16(h@W_b) via LDS-staged MFMA
    mfma_dual<<<gemmN64, 512, 0, stream>>>(h, Wta, Wtb, a16, b16, NN);

    // CSR degree + rank, then scan
    deg_hist<<<gE, 256, 0, stream>>>(ei, deg, rank);
    scan_part<<<g196, 256, 0, stream>>>(deg, part);
    scan_top<<<1, 64, 0, stream>>>(part, g196);
    scan_final<<<g196, 256, 0, stream>>>(deg, part, offs);

    // master scores + 4x8-bit LDS-privatized radix top-K
    score_fused<<<gemmN64, 256, 0, stream>>>(h_global, Wm1, bm1, Wm2, bm2, mscore);
    for (int lvl = 0; lvl < 4; ++lvl) {
        hist_pass<<<g196, 256, 0, stream>>>(mscore, state, lvl);
        hist_scan<<<1, 1, 0, stream>>>(state);
    }
    select_topk<<<g196, 256, 0, stream>>>(mscore, state, sel, tie_buf);
    tie_resolve<<<1, 256, 0, stream>>>(state, sel, tie_buf);
    build_master<<<KS, 128, 0, stream>>>(sel, h_global, pos, is_mast, inv, h_m, pos_m);

    // fused scatter (packed 4B) + master adjacency
    edge_scatter_adj<<<gE, 256, 0, stream>>>(ei, pos, offs, rank, is_mast, inv, eslot, adj_i);

    // gather-side edge aggregation
    edge_agg<<<(NN * 64) / 256, 256, 0, stream>>>(eslot, offs, deg, a16, b16, b1, u16, cw);

    // master attention -> B matrix
    qk_proj<<<KS, 64, 0, stream>>>(h_m, Wq, Wk, qm, km);
    attn_blend<<<KS, 512, 0, stream>>>(qm, km, adj_i, Bmat);

    // fused blend/virtual-adj/distance weight matrix (transposed) + row sums
    wmat_kernel<<<(KS * KS + 255) / 256, 256, 0, stream>>>(adj_i, Bmat, w_virt, pos_m, wT);
    cwm_kernel<<<KS, 64, 0, stream>>>(wT, cw_m);

    // dense backbone on masters
    gemm_dual<<<gemmK, 256, 0, stream>>>(h_m, W_a, W_b, a_m, bf_m, KS, 128);
    dense_agg<<<dim3(KS, NSL), 128, 0, stream>>>(a_m, bf_m, b1, wT, partial);
    master_update<<<KS, 128, 0, stream>>>(h_m, partial, cw_m, W2, b2, W3, b3, h_hier);

    // fused local output
    mfma_local_fused<<<gemmN64, 512, 0, stream>>>(h, u16, Wt3a, W23t, b23, b3, cw,
                                                  h_global, out, NN);

    // overwrite master rows of the global half
    gate_kernel<<<KS, 128, 0, stream>>>(sel, h_global, h_hier, Wa1, ba1, Wa2, ba2, out);
}

// Round 17
// 354.433 us; speedup vs baseline: 1.2286x; 1.0097x over previous
//
#include <hip/hip_runtime.h>
#include <math.h>

#define NN 50000
#define NE 800000
#define KS 500
#define NSL 8
#define SLICE 63

typedef unsigned short ushort_t;
typedef unsigned int uint_t;
typedef short bf16x8 __attribute__((ext_vector_type(8)));
typedef float f32x4 __attribute__((ext_vector_type(4)));

__device__ __forceinline__ float bf2f(ushort_t u) {
    return __uint_as_float(((uint_t)u) << 16);
}
__device__ __forceinline__ ushort_t f2bf(float f) {
    uint_t u = __float_as_uint(f);
    u += 0x7fffu + ((u >> 16) & 1u);   // round-to-nearest-even
    return (ushort_t)(u >> 16);
}
// fast silu: x * rcp(1+exp(-x)) using v_rcp_f32 (~1e-5 rel err) — NOT for the score path
__device__ __forceinline__ float fsilu(float x) {
    return x * __builtin_amdgcn_rcpf(1.f + __expf(-x));
}

// ============================ weight prep ============================
__global__ __launch_bounds__(128) void prep_wt(
    const float* __restrict__ Wa, const float* __restrict__ Wb, const float* __restrict__ W3,
    ushort_t* __restrict__ Wta, ushort_t* __restrict__ Wtb, ushort_t* __restrict__ Wt3a)
{
    int j = blockIdx.x;      // output row = original col
    int k = threadIdx.x;
    int y = blockIdx.y;
    const float* src = (y == 0) ? Wa : (y == 1) ? Wb : W3;
    ushort_t* dst = (y == 0) ? Wta : (y == 1) ? Wtb : Wt3a;
    dst[j * 128 + k] = f2bf(src[k * 128 + j]);
}

// W23t[j][c] = bf16(sum_k W2[c][k]*W3[128+k][j]); block 128 does b23[j]
__global__ __launch_bounds__(128) void w23t_kernel(
    const float* __restrict__ W2, const float* __restrict__ W3, const float* __restrict__ b2,
    ushort_t* __restrict__ W23t, float* __restrict__ b23)
{
    int c = blockIdx.x;
    int j = threadIdx.x;
    if (c < 128) {
        float acc = 0.f;
        for (int k = 0; k < 128; ++k) acc = fmaf(W2[c * 128 + k], W3[(128 + k) * 128 + j], acc);
        W23t[j * 128 + c] = f2bf(acc);
    } else {
        float acc = 0.f;
        for (int k = 0; k < 128; ++k) acc = fmaf(b2[k], W3[(128 + k) * 128 + j], acc);
        b23[j] = acc;
    }
}

// ============================ MFMA GEMM kernels ============================
// a16 = bf16(h@W_a), b16 = bf16(h@W_b). A-tile + per-kk weight K-slices staged in LDS.
__global__ __launch_bounds__(512) void mfma_dual(
    const float* __restrict__ h, const ushort_t* __restrict__ Wta, const ushort_t* __restrict__ Wtb,
    ushort_t* __restrict__ C1, ushort_t* __restrict__ C2, int M)
{
    __shared__ ushort_t As[64][136];
    __shared__ ushort_t Wa_s[128][40];
    __shared__ ushort_t Wb_s[128][40];
    const int t = threadIdx.x;
    const int bm = blockIdx.x * 64;
    for (int idx = t * 4; idx < 64 * 128; idx += 2048) {
        int r = idx >> 7, c = idx & 127;
        int gr = bm + r;
        float4 v = make_float4(0.f, 0.f, 0.f, 0.f);
        if (gr < M) v = *(const float4*)(h + (size_t)gr * 128 + c);
        As[r][c + 0] = f2bf(v.x); As[r][c + 1] = f2bf(v.y);
        As[r][c + 2] = f2bf(v.z); As[r][c + 3] = f2bf(v.w);
    }
    const int w = t >> 6;
    const int lane = t & 63;
    const int rowgrp = w >> 1;
    const int mat = w & 1;
    const int i = lane & 15, g = lane >> 4;
    const int row = rowgrp * 16 + i;
    const ushort_t* wsrc = (t < 256) ? Wta : Wtb;
    ushort_t* wdst0 = (t < 256) ? &Wa_s[0][0] : &Wb_s[0][0];
    const int tt = t & 255;
    const int wr = tt >> 1, wc = (tt & 1) * 16;

    f32x4 acc[8];
#pragma unroll
    for (int n = 0; n < 8; ++n) acc[n] = (f32x4)0.f;

#pragma unroll
    for (int kk = 0; kk < 4; ++kk) {
        __syncthreads();
        {
            uint4 v0 = *(const uint4*)(wsrc + (size_t)wr * 128 + kk * 32 + wc);
            uint4 v1 = *(const uint4*)(wsrc + (size_t)wr * 128 + kk * 32 + wc + 8);
            *(uint4*)(wdst0 + wr * 40 + wc) = v0;
            *(uint4*)(wdst0 + wr * 40 + wc + 8) = v1;
        }
        __syncthreads();
        const ushort_t* Ws = mat ? &Wb_s[0][0] : &Wa_s[0][0];
        bf16x8 af = *(const bf16x8*)(&As[row][kk * 32 + g * 8]);
#pragma unroll
        for (int n = 0; n < 8; ++n) {
            bf16x8 bf = *(const bf16x8*)(Ws + (n * 16 + i) * 40 + g * 8);
            acc[n] = __builtin_amdgcn_mfma_f32_16x16x32_bf16(af, bf, acc[n], 0, 0, 0);
        }
    }
    ushort_t* C = mat ? C2 : C1;
    const int R = bm + rowgrp * 16;
#pragma unroll
    for (int n = 0; n < 8; ++n) {
        int col = n * 16 + i;
#pragma unroll
        for (int v = 0; v < 4; ++v) {
            int orow = R + 4 * g + v;
            if (orow < M) C[(size_t)orow * 128 + col] = f2bf(acc[n][v]);
        }
    }
}

// out[:,0:128] = h + h@W3a + u16@W23 + cw*b23 + b3 ; out[:,128:256] = h_global
__global__ __launch_bounds__(512) void mfma_local_fused(
    const float* __restrict__ h, const ushort_t* __restrict__ u16,
    const ushort_t* __restrict__ Wt3a, const ushort_t* __restrict__ W23t,
    const float* __restrict__ b23, const float* __restrict__ b3,
    const float* __restrict__ cw, const float* __restrict__ h_global,
    float* __restrict__ out, int M)
{
    __shared__ ushort_t Hs[64][136];
    __shared__ ushort_t Us[64][136];
    __shared__ ushort_t W3s[128][40];
    __shared__ ushort_t W2s[128][40];
    const int t = threadIdx.x;
    const int bm = blockIdx.x * 64;
    for (int idx = t * 4; idx < 64 * 128; idx += 2048) {
        int r = idx >> 7, c = idx & 127;
        int gr = bm + r;
        float4 v = make_float4(0.f, 0.f, 0.f, 0.f);
        uint2 uv = make_uint2(0, 0);
        if (gr < M) {
            v = *(const float4*)(h + (size_t)gr * 128 + c);
            uv = *(const uint2*)(u16 + (size_t)gr * 128 + c);
            float4 hgv = *(const float4*)(h_global + (size_t)gr * 128 + c);
            *(float4*)(out + (size_t)gr * 256 + 128 + c) = hgv;   // global-half copy
        }
        Hs[r][c + 0] = f2bf(v.x); Hs[r][c + 1] = f2bf(v.y);
        Hs[r][c + 2] = f2bf(v.z); Hs[r][c + 3] = f2bf(v.w);
        Us[r][c + 0] = (ushort_t)(uv.x & 0xffff); Us[r][c + 1] = (ushort_t)(uv.x >> 16);
        Us[r][c + 2] = (ushort_t)(uv.y & 0xffff); Us[r][c + 3] = (ushort_t)(uv.y >> 16);
    }
    const int w = t >> 6;
    const int lane = t & 63;
    const int rowgrp = w >> 1;
    const int nb = (w & 1) * 4;
    const int i = lane & 15, g = lane >> 4;
    const int row = rowgrp * 16 + i;
    const ushort_t* wsrc = (t < 256) ? Wt3a : W23t;
    ushort_t* wdst0 = (t < 256) ? &W3s[0][0] : &W2s[0][0];
    const int tt = t & 255;
    const int wr = tt >> 1, wc = (tt & 1) * 16;

    f32x4 acc[4];
#pragma unroll
    for (int n = 0; n < 4; ++n) acc[n] = (f32x4)0.f;

#pragma unroll
    for (int kk = 0; kk < 4; ++kk) {
        __syncthreads();
        {
            uint4 v0 = *(const uint4*)(wsrc + (size_t)wr * 128 + kk * 32 + wc);
            uint4 v1 = *(const uint4*)(wsrc + (size_t)wr * 128 + kk * 32 + wc + 8);
            *(uint4*)(wdst0 + wr * 40 + wc) = v0;
            *(uint4*)(wdst0 + wr * 40 + wc + 8) = v1;
        }
        __syncthreads();
        bf16x8 aH = *(const bf16x8*)(&Hs[row][kk * 32 + g * 8]);
        bf16x8 aU = *(const bf16x8*)(&Us[row][kk * 32 + g * 8]);
#pragma unroll
        for (int n = 0; n < 4; ++n) {
            bf16x8 b3f = *(const bf16x8*)(&W3s[(nb + n) * 16 + i][g * 8]);
            bf16x8 b2f = *(const bf16x8*)(&W2s[(nb + n) * 16 + i][g * 8]);
            acc[n] = __builtin_amdgcn_mfma_f32_16x16x32_bf16(aH, b3f, acc[n], 0, 0, 0);
            acc[n] = __builtin_amdgcn_mfma_f32_16x16x32_bf16(aU, b2f, acc[n], 0, 0, 0);
        }
    }
    const int R = bm + rowgrp * 16;
    float cwv[4];
#pragma unroll
    for (int v = 0; v < 4; ++v) {
        int orow = R + 4 * g + v;
        cwv[v] = (orow < M) ? cw[orow] : 0.f;
    }
#pragma unroll
    for (int n = 0; n < 4; ++n) {
        int col = (nb + n) * 16 + i;
        float b3v = b3[col];
        float b23v = b23[col];
#pragma unroll
        for (int v = 0; v < 4; ++v) {
            int orow = R + 4 * g + v;
            if (orow < M) {
                float res = bf2f(Hs[rowgrp * 16 + 4 * g + v][col]);
                out[(size_t)orow * 256 + col] = acc[n][v] + b3v + cwv[v] * b23v + res;
            }
        }
    }
}

// fused fp32 score: mout = sigmoid(silu(hs@Wm1 + bm1)@Wm2 + bm2), hs = h_global[:, 0:64]
__global__ __launch_bounds__(256) void score_fused(
    const float* __restrict__ h_global, const float* __restrict__ Wm1,
    const float* __restrict__ bm1, const float* __restrict__ Wm2,
    const float* __restrict__ bm2, float* __restrict__ mout)
{
    __shared__ float Hs[64][64];
    const int t = threadIdx.x;
    const int bm = blockIdx.x * 64;
    for (int idx = t * 4; idx < 64 * 64; idx += 1024) {
        int r = idx >> 6, c = idx & 63;
        int gr = bm + r;
        float4 v = make_float4(0.f, 0.f, 0.f, 0.f);
        if (gr < NN) v = *(const float4*)(h_global + (size_t)gr * 128 + c);
        *(float4*)(&Hs[r][c]) = v;
    }
    __syncthreads();
    const int col = (t & 31) * 4;
    const int r0 = (t >> 5) * 8;
    float4 bmv = *(const float4*)(bm1 + col);
    float4 acc[8];
#pragma unroll
    for (int r = 0; r < 8; ++r) acc[r] = bmv;
    for (int k = 0; k < 64; ++k) {
        float4 w = *(const float4*)(Wm1 + k * 128 + col);
#pragma unroll
        for (int r = 0; r < 8; ++r) {
            float av = Hs[r0 + r][k];
            acc[r].x = fmaf(av, w.x, acc[r].x);
            acc[r].y = fmaf(av, w.y, acc[r].y);
            acc[r].z = fmaf(av, w.z, acc[r].z);
            acc[r].w = fmaf(av, w.w, acc[r].w);
        }
    }
    float4 w2v = *(const float4*)(Wm2 + col);
    float pr[8];
#pragma unroll
    for (int r = 0; r < 8; ++r) {
        float s = 0.f;
        s = fmaf(acc[r].x / (1.f + expf(-acc[r].x)), w2v.x, s);
        s = fmaf(acc[r].y / (1.f + expf(-acc[r].y)), w2v.y, s);
        s = fmaf(acc[r].z / (1.f + expf(-acc[r].z)), w2v.z, s);
        s = fmaf(acc[r].w / (1.f + expf(-acc[r].w)), w2v.w, s);
        pr[r] = s;
    }
#pragma unroll
    for (int off = 1; off < 32; off <<= 1) {
#pragma unroll
        for (int r = 0; r < 8; ++r) pr[r] += __shfl_xor(pr[r], off, 64);
    }
    if ((t & 31) == 0) {
        float bm2v = bm2[0];
#pragma unroll
        for (int r = 0; r < 8; ++r) {
            int gr = bm + r0 + r;
            if (gr < NN) mout[gr] = 1.f / (1.f + expf(-(pr[r] + bm2v)));
        }
    }
}

// f32 VALU gemm for the small master pass (KS=500)
__global__ __launch_bounds__(256) void gemm_dual(
    const float* __restrict__ A, const float* __restrict__ W1, const float* __restrict__ W2,
    float* __restrict__ C1, float* __restrict__ C2, int M, int ldc)
{
    __shared__ float As[64][128];
    const int t = threadIdx.x;
    const int bm = blockIdx.x * 64;
    for (int idx = t * 4; idx < 64 * 128; idx += 1024) {
        int r = idx >> 7, c = idx & 127;
        int gr = bm + r;
        float4 v = make_float4(0.f, 0.f, 0.f, 0.f);
        if (gr < M) v = *(const float4*)(A + (size_t)gr * 128 + c);
        *(float4*)(&As[r][c]) = v;
    }
    __syncthreads();
    const int col = (t & 31) * 4;
    const int r0 = (t >> 5) * 8;
    float4 acc1[8], acc2[8];
#pragma unroll
    for (int r = 0; r < 8; ++r) { acc1[r] = make_float4(0,0,0,0); acc2[r] = make_float4(0,0,0,0); }
    for (int k = 0; k < 128; ++k) {
        float4 w1 = *(const float4*)(W1 + k * 128 + col);
        float4 w2 = *(const float4*)(W2 + k * 128 + col);
#pragma unroll
        for (int r = 0; r < 8; ++r) {
            float av = As[r0 + r][k];
            acc1[r].x = fmaf(av, w1.x, acc1[r].x);
            acc1[r].y = fmaf(av, w1.y, acc1[r].y);
            acc1[r].z = fmaf(av, w1.z, acc1[r].z);
            acc1[r].w = fmaf(av, w1.w, acc1[r].w);
            acc2[r].x = fmaf(av, w2.x, acc2[r].x);
            acc2[r].y = fmaf(av, w2.y, acc2[r].y);
            acc2[r].z = fmaf(av, w2.z, acc2[r].z);
            acc2[r].w = fmaf(av, w2.w, acc2[r].w);
        }
    }
#pragma unroll
    for (int r = 0; r < 8; ++r) {
        int gr = bm + r0 + r;
        if (gr < M) {
            *(float4*)(C1 + (size_t)gr * ldc + col) = acc1[r];
            *(float4*)(C2 + (size_t)gr * ldc + col) = acc2[r];
        }
    }
}

// ============================ top-K (4x8-bit radix, LDS-privatized) ============================
// state layout: [0..255] bins, [256] prefix, [257] remaining, [258] gt counter, [259] tie counter
__global__ __launch_bounds__(256) void hist_pass(const float* __restrict__ m, int* state, int level)
{
    __shared__ int lh[256];
    lh[threadIdx.x] = 0;
    __syncthreads();
    int i = blockIdx.x * 256 + threadIdx.x;
    if (i == 0 && level == 0) state[257] = KS;
    if (i < NN) {
        unsigned v = __float_as_uint(m[i]);
        unsigned prefix = (unsigned)state[256];
        int shift = 32 - 8 * level;
        bool ok = (level == 0) || ((v >> shift) == prefix);
        if (ok) {
            unsigned byte = (v >> (shift - 8)) & 255u;
            atomicAdd(&lh[byte], 1);
        }
    }
    __syncthreads();
    if (lh[threadIdx.x]) atomicAdd(&state[threadIdx.x], lh[threadIdx.x]);
}

__global__ void hist_scan(int* state)
{
    int remaining = state[257];
    int cum = 0, bin = 0;
    for (int b = 255; b >= 0; --b) {
        int c = state[b];
        if (cum + c >= remaining) { bin = b; remaining -= cum; break; }
        cum += c;
    }
    state[256] = (int)(((unsigned)state[256] << 8) | (unsigned)bin);
    state[257] = remaining;
    for (int b = 0; b < 256; ++b) state[b] = 0;
}

__global__ __launch_bounds__(256) void select_topk(const float* __restrict__ m, int* state,
                                                   int* sel, int* tie_buf)
{
    int i = blockIdx.x * 256 + threadIdx.x;
    if (i >= NN) return;
    unsigned v = __float_as_uint(m[i]);
    unsigned T = (unsigned)state[256];
    if (v > T) {
        int p = atomicAdd(&state[258], 1);
        sel[p] = i;
    } else if (v == T) {
        int p = atomicAdd(&state[259], 1);
        if (p < 4096) tie_buf[p] = i;
    }
}

__global__ __launch_bounds__(256) void tie_resolve(int* state, int* sel, const int* tie_buf)
{
    int need = state[257];
    int cgt = state[258];
    int tcount = state[259];
    if (tcount > 4096) tcount = 4096;
    for (int t = threadIdx.x; t < tcount; t += blockDim.x) {
        int id = tie_buf[t];
        int rank = 0;
        for (int u = 0; u < tcount; ++u) rank += (tie_buf[u] < id);
        if (rank < need) sel[cgt + rank] = id;
    }
}

__global__ __launch_bounds__(128) void build_master(
    const int* __restrict__ sel, const float* __restrict__ h_global,
    const float* __restrict__ pos, int* __restrict__ is_master, int* __restrict__ inv,
    float* __restrict__ h_m, float* __restrict__ pos_m)
{
    int r = blockIdx.x;
    int t = threadIdx.x;
    int node = sel[r];
    if (t == 0) {
        is_master[node] = 1;
        inv[node] = r;
        pos_m[r * 3 + 0] = pos[(size_t)node * 3 + 0];
        pos_m[r * 3 + 1] = pos[(size_t)node * 3 + 1];
        pos_m[r * 3 + 2] = pos[(size_t)node * 3 + 2];
    }
    h_m[(size_t)r * 128 + t] = h_global[(size_t)node * 128 + t];
}

// ============================ CSR build (group edges by dst) ============================
__global__ __launch_bounds__(256) void deg_hist(const int* __restrict__ ei, int* __restrict__ deg,
                                                int* __restrict__ rank)
{
    int e = blockIdx.x * 256 + threadIdx.x;
    if (e < NE) rank[e] = atomicAdd(&deg[ei[NE + e]], 1);
}

__global__ __launch_bounds__(256) void scan_part(const int* __restrict__ deg, int* __restrict__ part)
{
    __shared__ int red[256];
    int i = blockIdx.x * 256 + threadIdx.x;
    red[threadIdx.x] = (i < NN) ? deg[i] : 0;
    __syncthreads();
    for (int off = 128; off > 0; off >>= 1) {
        if (threadIdx.x < off) red[threadIdx.x] += red[threadIdx.x + off];
        __syncthreads();
    }
    if (threadIdx.x == 0) part[blockIdx.x] = red[0];
}

__global__ void scan_top(int* part, int np)
{
    if (threadIdx.x == 0) {
        int run = 0;
        for (int i = 0; i < np; ++i) { int v = part[i]; part[i] = run; run += v; }
    }
}

__global__ __launch_bounds__(256) void scan_final(const int* __restrict__ deg, const int* __restrict__ part,
                                                  int* __restrict__ offs)
{
    __shared__ int sh[256];
    int i = blockIdx.x * 256 + threadIdx.x;
    int v = (i < NN) ? deg[i] : 0;
    sh[threadIdx.x] = v;
    __syncthreads();
    for (int off = 1; off < 256; off <<= 1) {
        int add = (threadIdx.x >= off) ? sh[threadIdx.x - off] : 0;
        __syncthreads();
        sh[threadIdx.x] += add;
        __syncthreads();
    }
    int excl = sh[threadIdx.x] - v + part[blockIdx.x];
    if (i < NN) offs[i] = excl;
}

// fused: scatter packed edge (src:16 | w:bf16) into slot offs[d]+rank[e] AND master adjacency
__global__ __launch_bounds__(256) void edge_scatter_adj(
    const int* __restrict__ ei, const float* __restrict__ pos,
    const int* __restrict__ offs, const int* __restrict__ rank,
    const int* __restrict__ is_master, const int* __restrict__ inv,
    uint_t* __restrict__ eslot, int* __restrict__ adj_i)
{
    int e = blockIdx.x * 256 + threadIdx.x;
    if (e >= NE) return;
    int s = ei[e];
    int d = ei[NE + e];
    float dx = pos[(size_t)s * 3 + 0] - pos[(size_t)d * 3 + 0];
    float dy = pos[(size_t)s * 3 + 1] - pos[(size_t)d * 3 + 1];
    float dz = pos[(size_t)s * 3 + 2] - pos[(size_t)d * 3 + 2];
    float w = 1.f / (1.f + dx * dx + dy * dy + dz * dz);
    eslot[offs[d] + rank[e]] = (uint_t)s | ((uint_t)f2bf(w) << 16);
    if (is_master[s] && is_master[d]) atomicOr(&adj_i[inv[s] * KS + inv[d]], 1);
}

// one wave per dst node: lane handles dims 2*lane, 2*lane+1; 8-edge batched unroll + fast silu
__global__ __launch_bounds__(256) void edge_agg(
    const uint_t* __restrict__ eslot, const int* __restrict__ offs, const int* __restrict__ deg,
    const ushort_t* __restrict__ a16, const ushort_t* __restrict__ b16,
    const float* __restrict__ b1, ushort_t* __restrict__ u16, float* __restrict__ cw)
{
    int wid = (blockIdx.x * 256 + threadIdx.x) >> 6;
    int lane = threadIdx.x & 63;
    if (wid >= NN) return;
    int off = offs[wid];
    int n = deg[wid];
    float2 b1v = *(const float2*)(b1 + 2 * lane);
    uint_t bw = ((const uint_t*)(b16 + (size_t)wid * 128))[lane];
    float bf0 = bf2f((ushort_t)(bw & 0xffff)) + b1v.x;
    float bf1 = bf2f((ushort_t)(bw >> 16)) + b1v.y;
    float acc0 = 0.f, acc1 = 0.f, cwa = 0.f;
    int k = 0;
    // 8-edge batched: issue all eslot loads, then all gathers, then compute
    for (; k + 8 <= n; k += 8) {
        uint_t e[8];
#pragma unroll
        for (int j = 0; j < 8; ++j) e[j] = eslot[off + k + j];
        uint_t aw[8];
#pragma unroll
        for (int j = 0; j < 8; ++j)
            aw[j] = ((const uint_t*)(a16 + (size_t)(e[j] & 0xffff) * 128))[lane];
#pragma unroll
        for (int j = 0; j < 8; ++j) {
            float wj = bf2f((ushort_t)(e[j] >> 16));
            acc0 = fmaf(fsilu(bf2f((ushort_t)(aw[j] & 0xffff)) + bf0), wj, acc0);
            acc1 = fmaf(fsilu(bf2f((ushort_t)(aw[j] >> 16)) + bf1), wj, acc1);
            cwa += wj;
        }
    }
    // 2-edge tail step
    for (; k + 2 <= n; k += 2) {
        uint_t e0 = eslot[off + k];
        uint_t e1 = eslot[off + k + 1];
        uint_t aw0 = ((const uint_t*)(a16 + (size_t)(e0 & 0xffff) * 128))[lane];
        uint_t aw1 = ((const uint_t*)(a16 + (size_t)(e1 & 0xffff) * 128))[lane];
        float w0 = bf2f((ushort_t)(e0 >> 16)), w1 = bf2f((ushort_t)(e1 >> 16));
        acc0 = fmaf(fsilu(bf2f((ushort_t)(aw0 & 0xffff)) + bf0), w0, acc0);
        acc1 = fmaf(fsilu(bf2f((ushort_t)(aw0 >> 16)) + bf1), w0, acc1);
        acc0 = fmaf(fsilu(bf2f((ushort_t)(aw1 & 0xffff)) + bf0), w1, acc0);
        acc1 = fmaf(fsilu(bf2f((ushort_t)(aw1 >> 16)) + bf1), w1, acc1);
        cwa += w0 + w1;
    }
    if (k < n) {
        uint_t e0 = eslot[off + k];
        uint_t aw0 = ((const uint_t*)(a16 + (size_t)(e0 & 0xffff) * 128))[lane];
        float w0 = bf2f((ushort_t)(e0 >> 16));
        acc0 = fmaf(fsilu(bf2f((ushort_t)(aw0 & 0xffff)) + bf0), w0, acc0);
        acc1 = fmaf(fsilu(bf2f((ushort_t)(aw0 >> 16)) + bf1), w0, acc1);
        cwa += w0;
    }
    uint_t packed = (uint_t)f2bf(acc0) | ((uint_t)f2bf(acc1) << 16);
    ((uint_t*)(u16 + (size_t)wid * 128))[lane] = packed;
    if (lane == 0) cw[wid] = cwa;
}

// ============================ master attention ============================
__global__ __launch_bounds__(64) void qk_proj(
    const float* __restrict__ h_m, const float* __restrict__ Wq, const float* __restrict__ Wk,
    float* __restrict__ q, float* __restrict__ kk)
{
    int r = blockIdx.x;
    int t = threadIdx.x;
    __shared__ float hs[64];
    hs[t] = h_m[(size_t)r * 128 + t];
    __syncthreads();
    float aq = 0.f, ak = 0.f;
    for (int s = 0; s < 64; ++s) {
        float hv = hs[s];
        aq = fmaf(hv, Wq[s * 64 + t], aq);
        ak = fmaf(hv, Wk[s * 64 + t], ak);
    }
    q[r * 64 + t] = aq;
    kk[r * 64 + t] = ak;
}

__global__ __launch_bounds__(512) void attn_blend(
    const float* __restrict__ q, const float* __restrict__ kk,
    const int* __restrict__ adj_i, int* __restrict__ B)
{
    int i = blockIdx.x;
    int t = threadIdx.x;
    __shared__ float qi[64];
    __shared__ float red[512];
    if (t < 64) qi[t] = q[i * 64 + t];
    __syncthreads();
    float s = -1e30f;
    if (t < KS) {
        float acc = 0.f;
        for (int c = 0; c < 64; ++c) acc = fmaf(qi[c], kk[t * 64 + c], acc);
        s = acc * 0.125f;
    }
    red[t] = s;
    __syncthreads();
    for (int off = 256; off > 0; off >>= 1) {
        if (t < off) red[t] = fmaxf(red[t], red[t + off]);
        __syncthreads();
    }
    float mx = red[0];
    __syncthreads();
    float e = (t < KS) ? expf(s - mx) : 0.f;
    red[t] = e;
    __syncthreads();
    for (int off = 256; off > 0; off >>= 1) {
        if (t < off) red[t] += red[t + off];
        __syncthreads();
    }
    float denom = red[0];
    if (t < KS) {
        float attn = e / denom;
        float blend = 0.5f * attn + 0.5f * (adj_i[i * KS + t] ? 1.f : 0.f);
        B[i * KS + t] = (blend > (1.f / (float)KS)) && (t != i);
    }
}

// wT[j][i] = (adj[i][j] + w_virtual*vadj[i][j]) / (1 + |pos_i - pos_j|^2)
__global__ __launch_bounds__(256) void wmat_kernel(
    const int* __restrict__ adj_i, const int* __restrict__ B,
    const float* __restrict__ w_virtual, const float* __restrict__ pos_m,
    float* __restrict__ wT)
{
    int idx = blockIdx.x * 256 + threadIdx.x;
    if (idx >= KS * KS) return;
    int j = idx / KS, i = idx % KS;
    int ij = i * KS + j;
    float adjf = adj_i[ij] ? 1.f : 0.f;
    float v = (B[ij] | B[j * KS + i]) ? 1.f : 0.f;
    float aw = adjf + w_virtual[0] * v;
    float dx = pos_m[i * 3 + 0] - pos_m[j * 3 + 0];
    float dy = pos_m[i * 3 + 1] - pos_m[j * 3 + 1];
    float dz = pos_m[i * 3 + 2] - pos_m[j * 3 + 2];
    wT[idx] = aw / (1.f + dx * dx + dy * dy + dz * dz);
}

__global__ __launch_bounds__(64) void cwm_kernel(const float* __restrict__ wT, float* __restrict__ cw_m)
{
    int j = blockIdx.x;
    int lane = threadIdx.x;
    float s = 0.f;
    for (int i = lane; i < KS; i += 64) s += wT[j * KS + i];
    for (int off = 32; off > 0; off >>= 1) s += __shfl_down(s, off);
    if (lane == 0) cw_m[j] = s;
}

// partial[sl][j][t] = sum_{i in slice sl} silu(a_m[i][t] + bf_m[j][t] + b1[t]) * wT[j][i]
__global__ __launch_bounds__(128) void dense_agg(
    const float* __restrict__ a_m, const float* __restrict__ bf_m,
    const float* __restrict__ b1, const float* __restrict__ wT,
    float* __restrict__ partial)
{
    int j = blockIdx.x;
    int sl = blockIdx.y;
    int t = threadIdx.x;
    int i0 = sl * SLICE;
    int i1 = min(KS, i0 + SLICE);
    float bfj = bf_m[(size_t)j * 128 + t] + b1[t];
    float acc = 0.f;
    for (int i = i0; i < i1; ++i) {
        float w = wT[j * KS + i];
        float x = a_m[(size_t)i * 128 + t] + bfj;
        acc = fmaf(fsilu(x), w, acc);
    }
    partial[((size_t)sl * KS + j) * 128 + t] = acc;
}

__global__ __launch_bounds__(128) void master_update(
    const float* __restrict__ h_m, const float* __restrict__ partial, const float* __restrict__ cw_m,
    const float* __restrict__ W2, const float* __restrict__ b2,
    const float* __restrict__ W3, const float* __restrict__ b3, float* __restrict__ h_hier)
{
    int j = blockIdx.x;
    int t = threadIdx.x;
    __shared__ float tsh[128], hsh[128], ash[128];
    float tv = 0.f;
#pragma unroll
    for (int sl = 0; sl < NSL; ++sl) tv += partial[((size_t)sl * KS + j) * 128 + t];
    tsh[t] = tv;
    hsh[t] = h_m[(size_t)j * 128 + t];
    __syncthreads();
    float acc = cw_m[j] * b2[t];
    for (int c = 0; c < 128; ++c) acc = fmaf(tsh[c], W2[c * 128 + t], acc);
    ash[t] = acc;
    __syncthreads();
    float upd = b3[t];
    for (int c = 0; c < 128; ++c) upd = fmaf(hsh[c], W3[c * 128 + t], upd);
    for (int c = 0; c < 128; ++c) upd = fmaf(ash[c], W3[(128 + c) * 128 + t], upd);
    h_hier[(size_t)j * 128 + t] = hsh[t] + upd;
}

__global__ __launch_bounds__(128) void gate_kernel(
    const int* __restrict__ sel, const float* __restrict__ h_global,
    const float* __restrict__ h_hier, const float* __restrict__ Wa1,
    const float* __restrict__ ba1, const float* __restrict__ Wa2,
    const float* __restrict__ ba2, float* __restrict__ out)
{
    int j = blockIdx.x;
    int t = threadIdx.x;
    int node = sel[j];
    __shared__ float x[256];
    __shared__ float g1[128];
    x[t] = h_global[(size_t)node * 128 + t];
    x[128 + t] = h_hier[(size_t)j * 128 + t];
    __syncthreads();
    float acc = ba1[t];
    for (int c = 0; c < 256; ++c) acc = fmaf(x[c], Wa1[c * 128 + t], acc);
    g1[t] = acc / (1.f + expf(-acc));
    __syncthreads();
    float g = ba2[t];
    for (int c = 0; c < 128; ++c) g = fmaf(g1[c], Wa2[c * 128 + t], g);
    out[(size_t)node * 256 + 128 + t] = x[t] + g * x[128 + t];
}

// ============================ launch ============================
extern "C" void kernel_launch(void* const* d_in, const int* in_sizes, int n_in,
                              void* d_out, int out_size, void* d_ws, size_t ws_size,
                              hipStream_t stream)
{
    const float* h        = (const float*)d_in[0];
    const float* h_global = (const float*)d_in[1];
    const float* pos      = (const float*)d_in[2];
    const int*   ei       = (const int*)d_in[3];
    const float* W_a      = (const float*)d_in[5];
    const float* W_b      = (const float*)d_in[6];
    const float* b1       = (const float*)d_in[7];
    const float* W2       = (const float*)d_in[8];
    const float* b2       = (const float*)d_in[9];
    const float* W3       = (const float*)d_in[10];
    const float* b3       = (const float*)d_in[11];
    const float* w_virt   = (const float*)d_in[12];
    const float* Wm1      = (const float*)d_in[13];
    const float* bm1      = (const float*)d_in[14];
    const float* Wm2      = (const float*)d_in[15];
    const float* bm2      = (const float*)d_in[16];
    const float* Wq       = (const float*)d_in[17];
    const float* Wk       = (const float*)d_in[18];
    const float* Wa1      = (const float*)d_in[19];
    const float* ba1      = (const float*)d_in[20];
    const float* Wa2      = (const float*)d_in[21];
    const float* ba2      = (const float*)d_in[22];
    float* out = (float*)d_out;

    // workspace carve
    char* p = (char*)d_ws;
    auto alloc = [&](size_t bytes) -> void* {
        void* q = (void*)p;
        p += (bytes + 255) & ~(size_t)255;
        return q;
    };
    // zeroed region (single memset): deg, is_mast, adj_i, state
    int*   deg      = (int*)alloc((size_t)NN * 4);
    int*   is_mast  = (int*)alloc((size_t)NN * 4);
    int*   adj_i    = (int*)alloc((size_t)KS * KS * 4);
    int*   state    = (int*)alloc(1024 * 4);
    char*  zero_end = p;
    size_t zero_bytes = (size_t)(zero_end - (char*)deg);

    ushort_t* u16   = (ushort_t*)alloc((size_t)NN * 128 * 2);
    float* mscore   = (float*)alloc((size_t)NN * 4);
    float* cw       = (float*)alloc((size_t)NN * 4);
    int*   inv      = (int*)alloc((size_t)NN * 4);
    int*   offs     = (int*)alloc((size_t)NN * 4);
    int*   rank     = (int*)alloc((size_t)NE * 4);
    uint_t* eslot   = (uint_t*)alloc((size_t)NE * 4);
    int*   part     = (int*)alloc(256 * 4);
    int*   sel      = (int*)alloc((size_t)KS * 4);
    float* h_m      = (float*)alloc((size_t)KS * 128 * 4);
    float* pos_m    = (float*)alloc((size_t)KS * 3 * 4);
    float* qm       = (float*)alloc((size_t)KS * 64 * 4);
    float* km       = (float*)alloc((size_t)KS * 64 * 4);
    int*   Bmat     = (int*)alloc((size_t)KS * KS * 4);
    float* wT       = (float*)alloc((size_t)KS * KS * 4);
    float* a_m      = (float*)alloc((size_t)KS * 128 * 4);
    float* bf_m     = (float*)alloc((size_t)KS * 128 * 4);
    float* partial  = (float*)alloc((size_t)NSL * KS * 128 * 4);
    float* cw_m     = (float*)alloc((size_t)KS * 4);
    float* h_hier   = (float*)alloc((size_t)KS * 128 * 4);
    ushort_t* Wta   = (ushort_t*)alloc(128 * 128 * 2);
    ushort_t* Wtb   = (ushort_t*)alloc(128 * 128 * 2);
    ushort_t* Wt3a  = (ushort_t*)alloc(128 * 128 * 2);
    ushort_t* W23t  = (ushort_t*)alloc(128 * 128 * 2);
    float* b23      = (float*)alloc(128 * 4);
    int*   tie_buf  = (int*)alloc(4096 * 4);

    // bf16 a / bf staged in d_out (overwritten later by mfma_local_fused)
    ushort_t* a16 = (ushort_t*)out;
    ushort_t* b16 = a16 + (size_t)NN * 128;

    hipMemsetAsync(deg, 0, zero_bytes, stream);

    const int gemmN64 = (NN + 63) / 64;  // 782
    const int gemmK = (KS + 63) / 64;
    const int g196 = (NN + 255) / 256;   // 196
    const int gE   = (NE + 255) / 256;   // 3125

    // weight prep
    prep_wt<<<dim3(128, 3), 128, 0, stream>>>(W_a, W_b, W3, Wta, Wtb, Wt3a);
    w23t_kernel<<<129, 128, 0, stream>>>(W2, W3, b2, W23t, b23);

    // a = bf16(h@W_a), bf = bf16(h@W_b) via LDS-staged MFMA
    mfma_dual<<<gemmN64, 512, 0, stream>>>(h, Wta, Wtb, a16, b16, NN);

    // CSR degree + rank, then scan
    deg_hist<<<gE, 256, 0, stream>>>(ei, deg, rank);
    scan_part<<<g196, 256, 0, stream>>>(deg, part);
    scan_top<<<1, 64, 0, stream>>>(part, g196);
    scan_final<<<g196, 256, 0, stream>>>(deg, part, offs);

    // master scores + 4x8-bit LDS-privatized radix top-K
    score_fused<<<gemmN64, 256, 0, stream>>>(h_global, Wm1, bm1, Wm2, bm2, mscore);
    for (int lvl = 0; lvl < 4; ++lvl) {
        hist_pass<<<g196, 256, 0, stream>>>(mscore, state, lvl);
        hist_scan<<<1, 1, 0, stream>>>(state);
    }
    select_topk<<<g196, 256, 0, stream>>>(mscore, state, sel, tie_buf);
    tie_resolve<<<1, 256, 0, stream>>>(state, sel, tie_buf);
    build_master<<<KS, 128, 0, stream>>>(sel, h_global, pos, is_mast, inv, h_m, pos_m);

    // fused scatter (packed 4B) + master adjacency
    edge_scatter_adj<<<gE, 256, 0, stream>>>(ei, pos, offs, rank, is_mast, inv, eslot, adj_i);

    // gather-side edge aggregation
    edge_agg<<<(NN * 64) / 256, 256, 0, stream>>>(eslot, offs, deg, a16, b16, b1, u16, cw);

    // master attention -> B matrix
    qk_proj<<<KS, 64, 0, stream>>>(h_m, Wq, Wk, qm, km);
    attn_blend<<<KS, 512, 0, stream>>>(qm, km, adj_i, Bmat);

    // fused blend/virtual-adj/distance weight matrix (transposed) + row sums
    wmat_kernel<<<(KS * KS + 255) / 256, 256, 0, stream>>>(adj_i, Bmat, w_virt, pos_m, wT);
    cwm_kernel<<<KS, 64, 0, stream>>>(wT, cw_m);

    // dense backbone on masters
    gemm_dual<<<gemmK, 256, 0, stream>>>(h_m, W_a, W_b, a_m, bf_m, KS, 128);
    dense_agg<<<dim3(KS, NSL), 128, 0, stream>>>(a_m, bf_m, b1, wT, partial);
    master_update<<<KS, 128, 0, stream>>>(h_m, partial, cw_m, W2, b2, W3, b3, h_hier);

    // fused local output
    mfma_local_fused<<<gemmN64, 512, 0, stream>>>(h, u16, Wt3a, W23t, b23, b3, cw,
                                                  h_global, out, NN);

    // overwrite master rows of the global half
    gate_kernel<<<KS, 128, 0, stream>>>(sel, h_global, h_hier, Wa1, ba1, Wa2, ba2, out);
}